// Round 4
// baseline (200.995 us; speedup 1.0000x reference)
//
#include <hip/hip_runtime.h>
#include <hip/hip_bf16.h>
#include <math.h>

#define L_ 8
#define B_ 2
#define N_ 512
#define D_ 1024
#define H_ 8
#define DH_ 64
#define INNER_ 512
#define M_ 16
#define BN_TOK 1024            // B_*N_
#define EPS 1.1920928955078125e-07f
#define SCALE_ 0.125f          // DH^-0.5

typedef __attribute__((ext_vector_type(8))) __bf16 bf16x8;
typedef __attribute__((ext_vector_type(4))) __bf16 bf16x4;
typedef __attribute__((ext_vector_type(4))) float f32x4;

#define BARF() do { __builtin_amdgcn_s_barrier(); __builtin_amdgcn_sched_barrier(0); } while (0)
#define GLL(SRC, DST) __builtin_amdgcn_global_load_lds( \
    (const __attribute__((address_space(1))) void*)(SRC), \
    (__attribute__((address_space(3))) void*)(DST), 16, 0, 0)

// ---------------------------------------------------------------------------
// Single-pass rs+gates+bf16-convert: one 256-thread block per (l,b,n) row.
// Each thread owns 4 consecutive d (one float4).
// ---------------------------------------------------------------------------
__global__ __launch_bounds__(256) void rs_gates_kernel(
    const float* __restrict__ tokens, const float* __restrict__ norm_w,
    const float* __restrict__ wg, float* __restrict__ gates_out,
    __bf16* __restrict__ tok_bf, __bf16* __restrict__ tn_bf)
{
    const int row = blockIdx.x;
    const int t = threadIdx.x;
    const int wave = t >> 6, lane = t & 63;
    __shared__ float wsum[4];
    __shared__ float wacc[4][8];

    const float4 v = ((const float4*)(tokens + (size_t)row * D_))[t];
    float ss = fmaf(v.x, v.x, fmaf(v.y, v.y, fmaf(v.z, v.z, v.w * v.w)));
    #pragma unroll
    for (int o = 1; o < 64; o <<= 1) ss += __shfl_xor(ss, o);
    if (lane == 0) wsum[wave] = ss;
    __syncthreads();
    const float rsv = rsqrtf((wsum[0] + wsum[1] + wsum[2] + wsum[3]) * (1.f / D_) + EPS);

    const float4 nw = ((const float4*)norm_w)[t];
    const float tn0 = v.x * rsv * nw.x, tn1 = v.y * rsv * nw.y;
    const float tn2 = v.z * rsv * nw.z, tn3 = v.w * rsv * nw.w;

    bf16x4 tb; tb.x = (__bf16)v.x; tb.y = (__bf16)v.y; tb.z = (__bf16)v.z; tb.w = (__bf16)v.w;
    ((bf16x4*)(tok_bf + (size_t)row * D_))[t] = tb;
    bf16x4 nb; nb.x = (__bf16)tn0; nb.y = (__bf16)tn1; nb.z = (__bf16)tn2; nb.w = (__bf16)tn3;
    ((bf16x4*)(tn_bf + (size_t)row * D_))[t] = nb;

    float acc[8];
    const float* w0 = wg + (size_t)(t * 4) * H_;
    #pragma unroll
    for (int h = 0; h < 8; ++h)
        acc[h] = fmaf(tn0, w0[h], fmaf(tn1, w0[8 + h], fmaf(tn2, w0[16 + h], tn3 * w0[24 + h])));
    #pragma unroll
    for (int h = 0; h < 8; ++h) {
        #pragma unroll
        for (int o = 1; o < 64; o <<= 1) acc[h] += __shfl_xor(acc[h], o);
    }
    if (lane == 0) {
        #pragma unroll
        for (int h = 0; h < 8; ++h) wacc[wave][h] = acc[h];
    }
    __syncthreads();
    if (t < 8) {
        float g = wacc[0][t] + wacc[1][t] + wacc[2][t] + wacc[3][t];
        gates_out[(size_t)row * H_ + t] = 1.f / (1.f + expf(-g));
    }
}

// ---------------------------------------------------------------------------
__global__ __launch_bounds__(256) void convert_bf16_kernel(
    const float* __restrict__ in, __bf16* __restrict__ out)
{
    const int i = blockIdx.x * 256 + threadIdx.x;
    float4 v = ((const float4*)in)[i];
    bf16x4 o;
    o.x = (__bf16)v.x; o.y = (__bf16)v.y; o.z = (__bf16)v.z; o.w = (__bf16)v.w;
    *(bf16x4*)(out + (size_t)i * 4) = o;
}

// ---------------------------------------------------------------------------
__global__ __launch_bounds__(256) void transpose_convert_kernel(
    const float* __restrict__ in, __bf16* __restrict__ out, int R, int C)
{
    __shared__ float tile[32][33];
    const int bx = blockIdx.x;     // C tile
    const int by = blockIdx.y;     // R tile
    const int x = threadIdx.x & 31, y = threadIdx.x >> 5;   // 32 x 8
    #pragma unroll
    for (int r = 0; r < 4; ++r)
        tile[y + r * 8][x] = in[(size_t)(by * 32 + y + r * 8) * C + bx * 32 + x];
    __syncthreads();
    #pragma unroll
    for (int r = 0; r < 4; ++r)
        out[(size_t)(bx * 32 + y + r * 8) * R + by * 32 + x] = (__bf16)tile[x][y + r * 8];
}

// ---------------------------------------------------------------------------
// 256x256 phased bf16 MFMA GEMM, C = A @ Bt^T.  A [M][K], Bt [N][K] row-major.
// BK=64, 512 threads = 8 waves (2m x 4n), wave tile 128x64, 16x16x32 MFMA.
// 2 LDS buffers; all frag ds_reads front-loaded in phases 1-2 of each K-tile,
// so buf[p] is free from phase 3 -> stage tile t+2's A into buf[p] (ph3-4),
// tile t+1's B into buf[p^1] (ph1-2).  Counted s_waitcnt vmcnt(4) once per
// K-tile (never 0 in steady state).  T2: chunk XOR (row&7) swizzle applied
// via pre-swizzled global source + XOR'd frag reads (LDS dest stays linear).
// MODE: 0 f32-out; 1 bf16-out; 2 per-l Bt + bias, bf16-out; 3 A row-gather
// (rows >= 8192 from A2), bf16-out.
// ---------------------------------------------------------------------------
template <int MODE>
__global__ __launch_bounds__(512, 2) void gemm_big(
    const __bf16* __restrict__ A, const __bf16* __restrict__ A2,
    const __bf16* __restrict__ Bt, const float* __restrict__ bias,
    void* __restrict__ Cout, int Ncols, int K, int NT, int ntx, int nty)
{
    __shared__ __align__(16) __bf16 As[2][256 * 64];   // 64 KiB
    __shared__ __align__(16) __bf16 Bs[2][256 * 64];   // 64 KiB

    const int tid = threadIdx.x;
    const int w = tid >> 6, lane = tid & 63;
    const int wm = w >> 2, wn = w & 3;
    const int fr = lane & 15, fq = lane >> 4;

    // XCD-aware tile decode (row-panel-sharing blocks land on one XCD)
    const int bid = blockIdx.x;
    const int c = bid & 7, s = bid >> 3;
    const int sq = s / ntx;
    const int m0 = (c * (nty >> 3) + sq) * 256;
    const int n0 = (s - sq * ntx) * 256;

    const __bf16* Ab = (MODE == 3 && m0 >= 8192) ? (A2 + (size_t)(m0 - 8192) * K)
                                                 : (A + (size_t)m0 * K);
    const __bf16* Btb = Bt + ((MODE == 2) ? ((size_t)(m0 >> 10) * Ncols * K) : (size_t)0)
                          + (size_t)n0 * K;

    // staging lane constants: each 1KB load covers 8 rows x 128B;
    // source chunk pre-swizzled so LDS(row, c) = global(row, c ^ (row&7)).
    const int lrow = lane >> 3;                 // row within 8-row group
    const int lchunk = (lane & 7) ^ lrow;       // swizzled 16B-chunk index
    // fragment LDS byte offsets (within a 128B row) for k-slice 0/1
    const int fo0 = ((fq ^ (lane & 7)) << 4);
    const int fo1 = (((4 + fq) ^ (lane & 7)) << 4);

#define STAGE_A(T2, PB, HALF) do {                                            \
    _Pragma("unroll")                                                         \
    for (int ld = (HALF) * 2; ld < (HALF) * 2 + 2; ++ld)                      \
        GLL(Ab + (size_t)(w * 32 + ld * 8 + lrow) * K + (T2) * 64 + lchunk * 8, \
            &As[PB][(w * 32 + ld * 8) * 64]);                                 \
} while (0)
#define STAGE_B(T2, PB, HALF) do {                                            \
    _Pragma("unroll")                                                         \
    for (int ld = (HALF) * 2; ld < (HALF) * 2 + 2; ++ld)                      \
        GLL(Btb + (size_t)(w * 32 + ld * 8 + lrow) * K + (T2) * 64 + lchunk * 8, \
            &Bs[PB][(w * 32 + ld * 8) * 64]);                                 \
} while (0)
#define READ_FRAGS(AFR, BFR, FO) do {                                         \
    _Pragma("unroll")                                                         \
    for (int mi = 0; mi < 8; ++mi)                                            \
        (AFR)[mi] = *(const bf16x8*)(Ap + ((wm * 128 + mi * 16 + fr) << 7) + (FO)); \
    _Pragma("unroll")                                                         \
    for (int nj = 0; nj < 4; ++nj)                                            \
        (BFR)[nj] = *(const bf16x8*)(Bp + ((wn * 64 + nj * 16 + fr) << 7) + (FO)); \
} while (0)
#define MFMA16(AOFF, AFR, BFR) do {                                           \
    _Pragma("unroll")                                                         \
    for (int mi = 0; mi < 4; ++mi)                                            \
        _Pragma("unroll")                                                     \
        for (int nj = 0; nj < 4; ++nj)                                        \
            acc[(AOFF) + mi][nj] = __builtin_amdgcn_mfma_f32_16x16x32_bf16(   \
                (AFR)[(AOFF) + mi], (BFR)[nj], acc[(AOFF) + mi][nj], 0, 0, 0); \
} while (0)

    f32x4 acc[8][4];
    #pragma unroll
    for (int mi = 0; mi < 8; ++mi)
        #pragma unroll
        for (int nj = 0; nj < 4; ++nj)
            acc[mi][nj] = (f32x4){0.f, 0.f, 0.f, 0.f};

    // prologue: tile0 A+B, tile1 A.  wait oldest 8 (tile0), leave tile1 A.
    STAGE_A(0, 0, 0); STAGE_A(0, 0, 1);
    STAGE_B(0, 0, 0); STAGE_B(0, 0, 1);
    STAGE_A(1, 1, 0); STAGE_A(1, 1, 1);
    asm volatile("s_waitcnt vmcnt(4)" ::: "memory");
    BARF();

    for (int t = 0; t < NT; ++t) {
        const int p = t & 1;
        const char* Ap = (const char*)&As[p][0];
        const char* Bp = (const char*)&Bs[p][0];
        bf16x8 af0[8], af1[8], bf0[4], bf1[4];

        // ---- phase 1: read k0 frags; stage B(t+1) half 0
        READ_FRAGS(af0, bf0, fo0);
        if (t + 1 < NT) STAGE_B(t + 1, p ^ 1, 0);
        BARF();
        __builtin_amdgcn_s_setprio(1);
        MFMA16(0, af0, bf0);
        __builtin_amdgcn_s_setprio(0);
        BARF();

        // ---- phase 2: read k1 frags; stage B(t+1) half 1
        READ_FRAGS(af1, bf1, fo1);
        if (t + 1 < NT) STAGE_B(t + 1, p ^ 1, 1);
        BARF();
        __builtin_amdgcn_s_setprio(1);
        MFMA16(4, af0, bf0);
        __builtin_amdgcn_s_setprio(0);
        // all reads of buf[p] must be complete before anyone passes this
        // barrier (phase 3 stages into As[p]):
        asm volatile("s_waitcnt lgkmcnt(0)" ::: "memory");
        BARF();

        // ---- phase 3: stage A(t+2) half 0 into buf p (free now)
        if (t + 2 < NT) STAGE_A(t + 2, p, 0);
        BARF();
        __builtin_amdgcn_s_setprio(1);
        MFMA16(0, af1, bf1);
        __builtin_amdgcn_s_setprio(0);
        BARF();

        // ---- phase 4: stage A(t+2) half 1; counted vmcnt; tile-end barrier
        if (t + 2 < NT) STAGE_A(t + 2, p, 1);
        BARF();
        __builtin_amdgcn_s_setprio(1);
        MFMA16(4, af1, bf1);
        __builtin_amdgcn_s_setprio(0);
        if (t + 2 < NT) { asm volatile("s_waitcnt vmcnt(4)" ::: "memory"); }
        else            { asm volatile("s_waitcnt vmcnt(0)" ::: "memory"); }
        BARF();
    }

    // epilogue: D mapping col=lane&15, row=(lane>>4)*4+reg
    #pragma unroll
    for (int mi = 0; mi < 8; ++mi) {
        const int r0 = m0 + wm * 128 + mi * 16 + fq * 4;
        #pragma unroll
        for (int nj = 0; nj < 4; ++nj) {
            const int col = n0 + wn * 64 + nj * 16 + fr;
            float badd = 0.f;
            if (MODE == 2) badd = bias[(size_t)(m0 >> 10) * Ncols + col];
            #pragma unroll
            for (int r = 0; r < 4; ++r) {
                float v = acc[mi][nj][r] + badd;
                if (MODE == 0)
                    ((float*)Cout)[(size_t)(r0 + r) * Ncols + col] = v;
                else
                    ((__bf16*)Cout)[(size_t)(r0 + r) * Ncols + col] = (__bf16)v;
            }
        }
    }
#undef STAGE_A
#undef STAGE_B
#undef READ_FRAGS
#undef MFMA16
}

// ---------------------------------------------------------------------------
// Attention kernel: one 64-thread block per (b,n,h) site (bf16 in/out).
// ---------------------------------------------------------------------------
__global__ __launch_bounds__(64) void attn_kernel(
    const __bf16* __restrict__ q,     // [8192, 512]
    const __bf16* __restrict__ kv,    // [16384, 1024]  (k | v)
    const float* __restrict__ gates,  // [8192, 8]
    const float* __restrict__ knw,    // [64]
    __bf16* __restrict__ og)          // [8192, 512]
{
    const int bid = blockIdx.x;
    const int c = bid & 7;
    const int s = bid >> 3;
    const int bn = c * 128 + (s >> 3);
    const int h = s & 7;
    const int t = threadIdx.x;

    __shared__ __align__(16) float qs[8][65];
    __shared__ __align__(16) float ks[16][65];
    __shared__ __align__(16) float vs[16][65];
    __shared__ float ss[8][17];
    __shared__ float kscale[16];
    __shared__ float gs[8];

    const float kw = knw[t];
    #pragma unroll
    for (int l = 0; l < 8; ++l)
        qs[l][t] = (float)q[((size_t)(l * BN_TOK + bn)) * INNER_ + h * DH_ + t] * kw;
    #pragma unroll
    for (int m = 0; m < 16; ++m) {
        const __bf16* kvrow = kv + ((size_t)(m * BN_TOK + bn)) * (2 * INNER_) + h * DH_;
        ks[m][t] = (float)kvrow[t];
        vs[m][t] = (float)kvrow[INNER_ + t];
    }
    if (t < 8) gs[t] = gates[((size_t)(t * BN_TOK + bn)) * H_ + h];
    __syncthreads();

    {
        int m = t & 15, grp = t >> 4;
        float s2 = 0.f;
        #pragma unroll
        for (int j = 0; j < 16; ++j) { float v = ks[m][grp * 16 + j]; s2 = fmaf(v, v, s2); }
        s2 += __shfl_xor(s2, 16);
        s2 += __shfl_xor(s2, 32);
        if (grp == 0) kscale[m] = rsqrtf(s2 * (1.f / DH_) + EPS);
    }
    __syncthreads();

    #pragma unroll
    for (int r = 0; r < 2; ++r) {
        int p = t + r * 64;
        int l = p >> 4, m = p & 15;
        float s2 = 0.f;
        #pragma unroll
        for (int d = 0; d < 64; ++d) s2 = fmaf(qs[l][d], ks[m][d], s2);
        ss[l][m] = s2 * kscale[m] * SCALE_;
    }
    __syncthreads();

    if (t < 8) {
        float mx = -1e30f;
        #pragma unroll
        for (int m = 0; m < 16; ++m) mx = fmaxf(mx, ss[t][m]);
        float sum = 0.f;
        #pragma unroll
        for (int m = 0; m < 16; ++m) { float e = expf(ss[t][m] - mx); ss[t][m] = e; sum += e; }
        float inv = 1.f / sum;
        #pragma unroll
        for (int m = 0; m < 16; ++m) ss[t][m] *= inv;
    }
    __syncthreads();

    #pragma unroll
    for (int l = 0; l < 8; ++l) {
        float o = 0.f;
        #pragma unroll
        for (int m = 0; m < 16; ++m) o = fmaf(ss[l][m], vs[m][t], o);
        og[((size_t)(l * BN_TOK + bn)) * INNER_ + h * DH_ + t] = (__bf16)(o * gs[l]);
    }
}

// ---------------------------------------------------------------------------
extern "C" void kernel_launch(void* const* d_in, const int* in_sizes, int n_in,
                              void* d_out, int out_size, void* d_ws, size_t ws_size,
                              hipStream_t stream)
{
    const float* tokens = (const float*)d_in[0];  // [8,2,512,1024]
    const float* w_net  = (const float*)d_in[1];  // [8,1024,1024]
    const float* b_net  = (const float*)d_in[2];  // [8,1024]
    const float* norm_w = (const float*)d_in[3];  // [1024]
    const float* wq     = (const float*)d_in[4];  // [1024,512]
    const float* wkv    = (const float*)d_in[5];  // [1024,1024]
    const float* knw    = (const float*)d_in[6];  // [64]
    const float* wg     = (const float*)d_in[7];  // [1024,8]
    const float* wout   = (const float*)d_in[8];  // [512,1024]
    float* out = (float*)d_out;                   // [8,2,512,1024]

    char* ws = (char*)d_ws;
    __bf16* tok_bf  = (__bf16*)(ws);                         // 16,777,216 B
    __bf16* tn_bf   = (__bf16*)(ws + 16777216);              // 16,777,216
    __bf16* out_bf  = (__bf16*)(ws + 33554432);              // 16,777,216
    __bf16* q_bf    = (__bf16*)(ws + 50331648);              //  8,388,608
    __bf16* kv_bf   = (__bf16*)(ws + 58720256);              // 33,554,432
    __bf16* og_bf   = (__bf16*)(ws + 92274688);              //  8,388,608
    __bf16* wnet_bf = (__bf16*)(ws + 100663296);             // 16,777,216
    __bf16* wqt_bf  = (__bf16*)(ws + 117440512);             //  1,048,576
    __bf16* wkvt_bf = (__bf16*)(ws + 118489088);             //  2,097,152
    __bf16* woutt_bf= (__bf16*)(ws + 120586240);             //  1,048,576
    float*  ws_g    = (float*)(ws + 121667584);              //    262,144

    rs_gates_kernel<<<L_ * BN_TOK, 256, 0, stream>>>(tokens, norm_w, wg, ws_g, tok_bf, tn_bf);
    convert_bf16_kernel<<<8192, 256, 0, stream>>>(w_net, wnet_bf);
    transpose_convert_kernel<<<dim3(16, 32), 256, 0, stream>>>(wq, wqt_bf, 1024, 512);
    transpose_convert_kernel<<<dim3(32, 32), 256, 0, stream>>>(wkv, wkvt_bf, 1024, 1024);
    transpose_convert_kernel<<<dim3(32, 16), 256, 0, stream>>>(wout, woutt_bf, 512, 1024);

    // member linear: out = tokens @ w_net^T + b_net  (M=8192, N=1024, K=1024)
    gemm_big<2><<<128, 512, 0, stream>>>(tok_bf, nullptr, wnet_bf, b_net,
                                         (void*)out_bf, 1024, 1024, 16, 4, 32);
    // q = tn @ wq  (M=8192, N=512, K=1024)
    gemm_big<1><<<64, 512, 0, stream>>>(tn_bf, nullptr, wqt_bf, nullptr,
                                        (void*)q_bf, 512, 1024, 16, 2, 32);
    // kv = ctx @ wkv  (M=16384 gathered, N=1024, K=1024)
    gemm_big<3><<<256, 512, 0, stream>>>(tok_bf, out_bf, wkvt_bf, nullptr,
                                         (void*)kv_bf, 1024, 1024, 16, 4, 64);
    // attention + gating
    attn_kernel<<<BN_TOK * H_, 64, 0, stream>>>(q_bf, kv_bf, ws_g, knw, og_bf);
    // pooled = og @ wout -> d_out (f32)  (M=8192, N=1024, K=512)
    gemm_big<0><<<128, 512, 0, stream>>>(og_bf, nullptr, woutt_bf, nullptr,
                                         (void*)out, 1024, 512, 8, 4, 32);
}

// Round 5
// 155.135 us; speedup vs baseline: 1.2956x; 1.2956x over previous
//
#include <hip/hip_runtime.h>
#include <hip/hip_bf16.h>
#include <math.h>

#define L_ 8
#define B_ 2
#define N_ 512
#define D_ 1024
#define H_ 8
#define DH_ 64
#define INNER_ 512
#define M_ 16
#define BN_TOK 1024            // B_*N_
#define EPS 1.1920928955078125e-07f
#define SCALE_ 0.125f          // DH^-0.5

typedef __attribute__((ext_vector_type(8))) __bf16 bf16x8;
typedef __attribute__((ext_vector_type(4))) __bf16 bf16x4;
typedef __attribute__((ext_vector_type(4))) float f32x4;

#define BARF() do { __builtin_amdgcn_s_barrier(); __builtin_amdgcn_sched_barrier(0); } while (0)
#define GLL(SRC, DST) __builtin_amdgcn_global_load_lds( \
    (const __attribute__((address_space(1))) void*)(SRC), \
    (__attribute__((address_space(3))) void*)(DST), 16, 0, 0)

// ---------------------------------------------------------------------------
// Streaming rms + bf16 convert: one 256-thread block per (l,b,n) row.
// No gates here (moved to MFMA mini-GEMM).
// ---------------------------------------------------------------------------
__global__ __launch_bounds__(256) void rs_kernel(
    const float* __restrict__ tokens, const float* __restrict__ norm_w,
    __bf16* __restrict__ tok_bf, __bf16* __restrict__ tn_bf)
{
    const int row = blockIdx.x;
    const int t = threadIdx.x;
    const int wave = t >> 6, lane = t & 63;
    __shared__ float wsum[4];

    const float4 v = ((const float4*)(tokens + (size_t)row * D_))[t];
    float ss = fmaf(v.x, v.x, fmaf(v.y, v.y, fmaf(v.z, v.z, v.w * v.w)));
    #pragma unroll
    for (int o = 1; o < 64; o <<= 1) ss += __shfl_xor(ss, o);
    if (lane == 0) wsum[wave] = ss;
    __syncthreads();
    const float rsv = rsqrtf((wsum[0] + wsum[1] + wsum[2] + wsum[3]) * (1.f / D_) + EPS);

    const float4 nw = ((const float4*)norm_w)[t];
    bf16x4 tb; tb.x = (__bf16)v.x; tb.y = (__bf16)v.y; tb.z = (__bf16)v.z; tb.w = (__bf16)v.w;
    ((bf16x4*)(tok_bf + (size_t)row * D_))[t] = tb;
    bf16x4 nb;
    nb.x = (__bf16)(v.x * rsv * nw.x); nb.y = (__bf16)(v.y * rsv * nw.y);
    nb.z = (__bf16)(v.z * rsv * nw.z); nb.w = (__bf16)(v.w * rsv * nw.w);
    ((bf16x4*)(tn_bf + (size_t)row * D_))[t] = nb;
}

// ---------------------------------------------------------------------------
// wgT build: wg [1024][8] f32 -> wgT [16][1024] bf16, rows 8..15 zero.
// ---------------------------------------------------------------------------
__global__ __launch_bounds__(256) void wgT_kernel(
    const float* __restrict__ wg, __bf16* __restrict__ wgT)
{
    const int g = blockIdx.x * 256 + threadIdx.x;   // 64 blocks -> 16384
    const int h = g >> 10, d = g & 1023;
    wgT[g] = (h < 8) ? (__bf16)wg[d * 8 + h] : (__bf16)0.f;
}

// ---------------------------------------------------------------------------
// gates = sigmoid(tn @ wg) via MFMA: one wave per 16 rows, K=1024.
// B = wgT [16][1024] (cols 8..15 zero, discarded).
// ---------------------------------------------------------------------------
__global__ __launch_bounds__(256) void gates_kernel(
    const __bf16* __restrict__ tn, const __bf16* __restrict__ wgT,
    float* __restrict__ gates_out)
{
    const int w = threadIdx.x >> 6, lane = threadIdx.x & 63;
    const int fr = lane & 15, fq = lane >> 4;
    const int r0 = blockIdx.x * 64 + w * 16;
    const __bf16* arow = tn + (size_t)(r0 + fr) * D_ + fq * 8;
    const __bf16* brow = wgT + (size_t)fr * D_ + fq * 8;
    f32x4 acc = (f32x4){0.f, 0.f, 0.f, 0.f};
    #pragma unroll 8
    for (int k0 = 0; k0 < D_; k0 += 32) {
        bf16x8 a = *(const bf16x8*)(arow + k0);
        bf16x8 b = *(const bf16x8*)(brow + k0);
        acc = __builtin_amdgcn_mfma_f32_16x16x32_bf16(a, b, acc, 0, 0, 0);
    }
    if (fr < 8) {
        #pragma unroll
        for (int r = 0; r < 4; ++r)
            gates_out[(size_t)(r0 + fq * 4 + r) * H_ + fr] = 1.f / (1.f + expf(-acc[r]));
    }
}

// ---------------------------------------------------------------------------
__global__ __launch_bounds__(256) void convert_bf16_kernel(
    const float* __restrict__ in, __bf16* __restrict__ out)
{
    const int i = blockIdx.x * 256 + threadIdx.x;
    float4 v = ((const float4*)in)[i];
    bf16x4 o;
    o.x = (__bf16)v.x; o.y = (__bf16)v.y; o.z = (__bf16)v.z; o.w = (__bf16)v.w;
    *(bf16x4*)(out + (size_t)i * 4) = o;
}

// ---------------------------------------------------------------------------
__global__ __launch_bounds__(256) void transpose_convert_kernel(
    const float* __restrict__ in, __bf16* __restrict__ out, int R, int C)
{
    __shared__ float tile[32][33];
    const int bx = blockIdx.x;     // C tile
    const int by = blockIdx.y;     // R tile
    const int x = threadIdx.x & 31, y = threadIdx.x >> 5;   // 32 x 8
    #pragma unroll
    for (int r = 0; r < 4; ++r)
        tile[y + r * 8][x] = in[(size_t)(by * 32 + y + r * 8) * C + bx * 32 + x];
    __syncthreads();
    #pragma unroll
    for (int r = 0; r < 4; ++r)
        out[(size_t)(bx * 32 + y + r * 8) * R + by * 32 + x] = (__bf16)tile[x][y + r * 8];
}

// ---------------------------------------------------------------------------
// 256x256 phased bf16 MFMA GEMM, C = A @ Bt^T.  A [M][K], Bt [N][K] row-major.
// BK=64, 512 threads = 8 waves (2m x 4n), wave tile 128x64, 16x16x32 MFMA.
// Phased counted-vmcnt schedule + T2 swizzle + T5 setprio (sync structure
// unchanged from round 4 -- verified).
// MODE: 0 final (f32 out, K=512); 3 kv (A row-gather at 8192, bf16 out);
// 4 fused member+q (block-uniform select: bid<128 member w/ per-l Bt+bias,
// else q), bf16 out.
// ---------------------------------------------------------------------------
template <int MODE>
__global__ __launch_bounds__(512, 2) void gemm_big(
    const __bf16* __restrict__ A, const __bf16* __restrict__ A2,
    const __bf16* __restrict__ Bt, const __bf16* __restrict__ Bt2,
    const float* __restrict__ bias,
    void* __restrict__ Cout, void* __restrict__ Cout2)
{
    __shared__ __align__(16) __bf16 As[2][256 * 64];   // 64 KiB
    __shared__ __align__(16) __bf16 Bs[2][256 * 64];   // 64 KiB

    constexpr int NT = (MODE == 0) ? 8 : 16;           // K = NT*64
    constexpr int K = NT * 64;

    const int tid = threadIdx.x;
    const int w = tid >> 6, lane = tid & 63;
    const int wm = w >> 2, wn = w & 3;
    const int fr = lane & 15, fq = lane >> 4;

    // ---- per-mode geometry (block-uniform) + XCD-aware decode
    const int bid = blockIdx.x;
    int m0, n0, Ncols;
    const __bf16 *Ab, *Btb;
    const float* biasp = nullptr;
    void* Co;

    if (MODE == 4) {
        const bool isq = bid >= 128;
        const int b2 = isq ? bid - 128 : bid;
        const int ntx = isq ? 2 : 4;
        const int c = b2 & 7, s = b2 >> 3;
        const int sq = s / ntx;
        m0 = (c * 4 + sq) * 256;
        n0 = (s - sq * ntx) * 256;
        if (isq) {
            Ab = A2 + (size_t)m0 * K; Btb = Bt2 + (size_t)n0 * K;
            Co = Cout2; Ncols = 512;
        } else {
            Ab = A + (size_t)m0 * K;
            Btb = Bt + (size_t)(m0 >> 10) * 1024 * K + (size_t)n0 * K;
            Co = Cout; Ncols = 1024;
            biasp = bias + (size_t)(m0 >> 10) * 1024;
        }
    } else {
        const int ntx = 4;                             // N=1024 both
        const int nty8 = (MODE == 3) ? 8 : 4;          // nty/8
        const int c = bid & 7, s = bid >> 3;
        const int sq = s / ntx;
        m0 = (c * nty8 + sq) * 256;
        n0 = (s - sq * ntx) * 256;
        Ncols = 1024;
        Co = Cout;
        if (MODE == 3)
            Ab = (m0 >= 8192) ? (A2 + (size_t)(m0 - 8192) * K) : (A + (size_t)m0 * K);
        else
            Ab = A + (size_t)m0 * K;
        Btb = Bt + (size_t)n0 * K;
    }

    // staging lane constants (T2 swizzle via pre-swizzled global source)
    const int lrow = lane >> 3;
    const int lchunk = (lane & 7) ^ lrow;
    const int fo0 = ((fq ^ (lane & 7)) << 4);
    const int fo1 = (((4 + fq) ^ (lane & 7)) << 4);

#define STAGE_A(T2, PB, HALF) do {                                            \
    _Pragma("unroll")                                                         \
    for (int ld = (HALF) * 2; ld < (HALF) * 2 + 2; ++ld)                      \
        GLL(Ab + (size_t)(w * 32 + ld * 8 + lrow) * K + (T2) * 64 + lchunk * 8, \
            &As[PB][(w * 32 + ld * 8) * 64]);                                 \
} while (0)
#define STAGE_B(T2, PB, HALF) do {                                            \
    _Pragma("unroll")                                                         \
    for (int ld = (HALF) * 2; ld < (HALF) * 2 + 2; ++ld)                      \
        GLL(Btb + (size_t)(w * 32 + ld * 8 + lrow) * K + (T2) * 64 + lchunk * 8, \
            &Bs[PB][(w * 32 + ld * 8) * 64]);                                 \
} while (0)
#define READ_FRAGS(AFR, BFR, FO) do {                                         \
    _Pragma("unroll")                                                         \
    for (int mi = 0; mi < 8; ++mi)                                            \
        (AFR)[mi] = *(const bf16x8*)(Ap + ((wm * 128 + mi * 16 + fr) << 7) + (FO)); \
    _Pragma("unroll")                                                         \
    for (int nj = 0; nj < 4; ++nj)                                            \
        (BFR)[nj] = *(const bf16x8*)(Bp + ((wn * 64 + nj * 16 + fr) << 7) + (FO)); \
} while (0)
#define MFMA16(AOFF, AFR, BFR) do {                                           \
    _Pragma("unroll")                                                         \
    for (int mi = 0; mi < 4; ++mi)                                            \
        _Pragma("unroll")                                                     \
        for (int nj = 0; nj < 4; ++nj)                                        \
            acc[(AOFF) + mi][nj] = __builtin_amdgcn_mfma_f32_16x16x32_bf16(   \
                (AFR)[(AOFF) + mi], (BFR)[nj], acc[(AOFF) + mi][nj], 0, 0, 0); \
} while (0)

    f32x4 acc[8][4];
    #pragma unroll
    for (int mi = 0; mi < 8; ++mi)
        #pragma unroll
        for (int nj = 0; nj < 4; ++nj)
            acc[mi][nj] = (f32x4){0.f, 0.f, 0.f, 0.f};

    // prologue: tile0 A+B, tile1 A.  wait oldest 8 (tile0), leave tile1 A.
    STAGE_A(0, 0, 0); STAGE_A(0, 0, 1);
    STAGE_B(0, 0, 0); STAGE_B(0, 0, 1);
    STAGE_A(1, 1, 0); STAGE_A(1, 1, 1);
    asm volatile("s_waitcnt vmcnt(4)" ::: "memory");
    BARF();

    for (int t = 0; t < NT; ++t) {
        const int p = t & 1;
        const char* Ap = (const char*)&As[p][0];
        const char* Bp = (const char*)&Bs[p][0];
        bf16x8 af0[8], af1[8], bf0[4], bf1[4];

        // ---- phase 1: read k0 frags; stage B(t+1) half 0
        READ_FRAGS(af0, bf0, fo0);
        if (t + 1 < NT) STAGE_B(t + 1, p ^ 1, 0);
        BARF();
        __builtin_amdgcn_s_setprio(1);
        MFMA16(0, af0, bf0);
        __builtin_amdgcn_s_setprio(0);
        BARF();

        // ---- phase 2: read k1 frags; stage B(t+1) half 1
        READ_FRAGS(af1, bf1, fo1);
        if (t + 1 < NT) STAGE_B(t + 1, p ^ 1, 1);
        BARF();
        __builtin_amdgcn_s_setprio(1);
        MFMA16(4, af0, bf0);
        __builtin_amdgcn_s_setprio(0);
        asm volatile("s_waitcnt lgkmcnt(0)" ::: "memory");
        BARF();

        // ---- phase 3: stage A(t+2) half 0 into buf p (free now)
        if (t + 2 < NT) STAGE_A(t + 2, p, 0);
        BARF();
        __builtin_amdgcn_s_setprio(1);
        MFMA16(0, af1, bf1);
        __builtin_amdgcn_s_setprio(0);
        BARF();

        // ---- phase 4: stage A(t+2) half 1; counted vmcnt; tile-end barrier
        if (t + 2 < NT) STAGE_A(t + 2, p, 1);
        BARF();
        __builtin_amdgcn_s_setprio(1);
        MFMA16(4, af1, bf1);
        __builtin_amdgcn_s_setprio(0);
        if (t + 2 < NT) { asm volatile("s_waitcnt vmcnt(4)" ::: "memory"); }
        else            { asm volatile("s_waitcnt vmcnt(0)" ::: "memory"); }
        BARF();
    }

    // epilogue: D mapping col=lane&15, row=(lane>>4)*4+reg
    #pragma unroll
    for (int mi = 0; mi < 8; ++mi) {
        const int r0 = m0 + wm * 128 + mi * 16 + fq * 4;
        #pragma unroll
        for (int nj = 0; nj < 4; ++nj) {
            const int col = n0 + wn * 64 + nj * 16 + fr;
            const float badd = (MODE == 4 && biasp != nullptr) ? biasp[col] : 0.f;
            #pragma unroll
            for (int r = 0; r < 4; ++r) {
                float v = acc[mi][nj][r] + badd;
                if (MODE == 0)
                    ((float*)Co)[(size_t)(r0 + r) * Ncols + col] = v;
                else
                    ((__bf16*)Co)[(size_t)(r0 + r) * Ncols + col] = (__bf16)v;
            }
        }
    }
#undef STAGE_A
#undef STAGE_B
#undef READ_FRAGS
#undef MFMA16
}

// ---------------------------------------------------------------------------
// Attention kernel: one 64-thread block per (b,n,h) site (bf16 in/out).
// ---------------------------------------------------------------------------
__global__ __launch_bounds__(64) void attn_kernel(
    const __bf16* __restrict__ q,     // [8192, 512]
    const __bf16* __restrict__ kv,    // [16384, 1024]  (k | v)
    const float* __restrict__ gates,  // [8192, 8]
    const float* __restrict__ knw,    // [64]
    __bf16* __restrict__ og)          // [8192, 512]
{
    const int bid = blockIdx.x;
    const int c = bid & 7;
    const int s = bid >> 3;
    const int bn = c * 128 + (s >> 3);
    const int h = s & 7;
    const int t = threadIdx.x;

    __shared__ __align__(16) float qs[8][65];
    __shared__ __align__(16) float ks[16][65];
    __shared__ __align__(16) float vs[16][65];
    __shared__ float ss[8][17];
    __shared__ float kscale[16];
    __shared__ float gs[8];

    const float kw = knw[t];
    #pragma unroll
    for (int l = 0; l < 8; ++l)
        qs[l][t] = (float)q[((size_t)(l * BN_TOK + bn)) * INNER_ + h * DH_ + t] * kw;
    #pragma unroll
    for (int m = 0; m < 16; ++m) {
        const __bf16* kvrow = kv + ((size_t)(m * BN_TOK + bn)) * (2 * INNER_) + h * DH_;
        ks[m][t] = (float)kvrow[t];
        vs[m][t] = (float)kvrow[INNER_ + t];
    }
    if (t < 8) gs[t] = gates[((size_t)(t * BN_TOK + bn)) * H_ + h];
    __syncthreads();

    {
        int m = t & 15, grp = t >> 4;
        float s2 = 0.f;
        #pragma unroll
        for (int j = 0; j < 16; ++j) { float v = ks[m][grp * 16 + j]; s2 = fmaf(v, v, s2); }
        s2 += __shfl_xor(s2, 16);
        s2 += __shfl_xor(s2, 32);
        if (grp == 0) kscale[m] = rsqrtf(s2 * (1.f / DH_) + EPS);
    }
    __syncthreads();

    #pragma unroll
    for (int r = 0; r < 2; ++r) {
        int p = t + r * 64;
        int l = p >> 4, m = p & 15;
        float s2 = 0.f;
        #pragma unroll
        for (int d = 0; d < 64; ++d) s2 = fmaf(qs[l][d], ks[m][d], s2);
        ss[l][m] = s2 * kscale[m] * SCALE_;
    }
    __syncthreads();

    if (t < 8) {
        float mx = -1e30f;
        #pragma unroll
        for (int m = 0; m < 16; ++m) mx = fmaxf(mx, ss[t][m]);
        float sum = 0.f;
        #pragma unroll
        for (int m = 0; m < 16; ++m) { float e = expf(ss[t][m] - mx); ss[t][m] = e; sum += e; }
        float inv = 1.f / sum;
        #pragma unroll
        for (int m = 0; m < 16; ++m) ss[t][m] *= inv;
    }
    __syncthreads();

    #pragma unroll
    for (int l = 0; l < 8; ++l) {
        float o = 0.f;
        #pragma unroll
        for (int m = 0; m < 16; ++m) o = fmaf(ss[l][m], vs[m][t], o);
        og[((size_t)(l * BN_TOK + bn)) * INNER_ + h * DH_ + t] = (__bf16)(o * gs[l]);
    }
}

// ---------------------------------------------------------------------------
extern "C" void kernel_launch(void* const* d_in, const int* in_sizes, int n_in,
                              void* d_out, int out_size, void* d_ws, size_t ws_size,
                              hipStream_t stream)
{
    const float* tokens = (const float*)d_in[0];  // [8,2,512,1024]
    const float* w_net  = (const float*)d_in[1];  // [8,1024,1024]
    const float* b_net  = (const float*)d_in[2];  // [8,1024]
    const float* norm_w = (const float*)d_in[3];  // [1024]
    const float* wq     = (const float*)d_in[4];  // [1024,512]
    const float* wkv    = (const float*)d_in[5];  // [1024,1024]
    const float* knw    = (const float*)d_in[6];  // [64]
    const float* wg     = (const float*)d_in[7];  // [1024,8]
    const float* wout   = (const float*)d_in[8];  // [512,1024]
    float* out = (float*)d_out;                   // [8,2,512,1024]

    char* ws = (char*)d_ws;
    __bf16* tok_bf  = (__bf16*)(ws);                         // 16,777,216 B
    __bf16* tn_bf   = (__bf16*)(ws + 16777216);              // 16,777,216
    __bf16* out_bf  = (__bf16*)(ws + 33554432);              // 16,777,216
    __bf16* q_bf    = (__bf16*)(ws + 50331648);              //  8,388,608
    __bf16* kv_bf   = (__bf16*)(ws + 58720256);              // 33,554,432
    __bf16* og_bf   = (__bf16*)(ws + 92274688);              //  8,388,608
    __bf16* wnet_bf = (__bf16*)(ws + 100663296);             // 16,777,216
    __bf16* wqt_bf  = (__bf16*)(ws + 117440512);             //  1,048,576
    __bf16* wkvt_bf = (__bf16*)(ws + 118489088);             //  2,097,152
    __bf16* woutt_bf= (__bf16*)(ws + 120586240);             //  1,048,576
    float*  ws_g    = (float*)(ws + 121667584);              //    262,144
    __bf16* wgT_bf  = (__bf16*)(ws + 121929728);             //     32,768

    // streaming rms + bf16 converts
    rs_kernel<<<L_ * BN_TOK, 256, 0, stream>>>(tokens, norm_w, tok_bf, tn_bf);
    // weight prep
    convert_bf16_kernel<<<8192, 256, 0, stream>>>(w_net, wnet_bf);
    transpose_convert_kernel<<<dim3(16, 32), 256, 0, stream>>>(wq, wqt_bf, 1024, 512);
    transpose_convert_kernel<<<dim3(32, 32), 256, 0, stream>>>(wkv, wkvt_bf, 1024, 1024);
    transpose_convert_kernel<<<dim3(32, 16), 256, 0, stream>>>(wout, woutt_bf, 512, 1024);
    wgT_kernel<<<64, 256, 0, stream>>>(wg, wgT_bf);

    // gates = sigmoid(tn @ wg)  (MFMA mini-GEMM)
    gates_kernel<<<128, 256, 0, stream>>>(tn_bf, wgT_bf, ws_g);

    // fused member linear + q projection (192 blocks, one round)
    gemm_big<4><<<192, 512, 0, stream>>>(tok_bf, tn_bf, wnet_bf, wqt_bf, b_net,
                                         (void*)out_bf, (void*)q_bf);
    // kv = ctx @ wkv  (M=16384 gathered, N=1024, K=1024)
    gemm_big<3><<<256, 512, 0, stream>>>(tok_bf, out_bf, wkvt_bf, nullptr, nullptr,
                                         (void*)kv_bf, nullptr);
    // attention + gating
    attn_kernel<<<BN_TOK * H_, 64, 0, stream>>>(q_bf, kv_bf, ws_g, knw, og_bf);
    // pooled = og @ wout -> d_out (f32)  (M=8192, N=1024, K=512)
    gemm_big<0><<<128, 512, 0, stream>>>(og_bf, nullptr, woutt_bf, nullptr, nullptr,
                                         (void*)out, nullptr);
}

// Round 6
// 150.081 us; speedup vs baseline: 1.3392x; 1.0337x over previous
//
#include <hip/hip_runtime.h>
#include <hip/hip_bf16.h>
#include <math.h>

#define L_ 8
#define B_ 2
#define N_ 512
#define D_ 1024
#define H_ 8
#define DH_ 64
#define INNER_ 512
#define M_ 16
#define BN_TOK 1024            // B_*N_
#define EPS 1.1920928955078125e-07f
#define SCALE_ 0.125f          // DH^-0.5

typedef __attribute__((ext_vector_type(8))) __bf16 bf16x8;
typedef __attribute__((ext_vector_type(4))) __bf16 bf16x4;
typedef __attribute__((ext_vector_type(4))) float f32x4;

#define BARF() do { __builtin_amdgcn_s_barrier(); __builtin_amdgcn_sched_barrier(0); } while (0)
#define GLL(SRC, DST) __builtin_amdgcn_global_load_lds( \
    (const __attribute__((address_space(1))) void*)(SRC), \
    (__attribute__((address_space(3))) void*)(DST), 16, 0, 0)

// ---------------------------------------------------------------------------
// Streaming rms + bf16 convert: one 256-thread block per (l,b,n) row.
// ---------------------------------------------------------------------------
__global__ __launch_bounds__(256) void rs_kernel(
    const float* __restrict__ tokens, const float* __restrict__ norm_w,
    __bf16* __restrict__ tok_bf, __bf16* __restrict__ tn_bf)
{
    const int row = blockIdx.x;
    const int t = threadIdx.x;
    const int wave = t >> 6, lane = t & 63;
    __shared__ float wsum[4];

    const float4 v = ((const float4*)(tokens + (size_t)row * D_))[t];
    float ss = fmaf(v.x, v.x, fmaf(v.y, v.y, fmaf(v.z, v.z, v.w * v.w)));
    #pragma unroll
    for (int o = 1; o < 64; o <<= 1) ss += __shfl_xor(ss, o);
    if (lane == 0) wsum[wave] = ss;
    __syncthreads();
    const float rsv = rsqrtf((wsum[0] + wsum[1] + wsum[2] + wsum[3]) * (1.f / D_) + EPS);

    const float4 nw = ((const float4*)norm_w)[t];
    bf16x4 tb; tb.x = (__bf16)v.x; tb.y = (__bf16)v.y; tb.z = (__bf16)v.z; tb.w = (__bf16)v.w;
    ((bf16x4*)(tok_bf + (size_t)row * D_))[t] = tb;
    bf16x4 nb;
    nb.x = (__bf16)(v.x * rsv * nw.x); nb.y = (__bf16)(v.y * rsv * nw.y);
    nb.z = (__bf16)(v.z * rsv * nw.z); nb.w = (__bf16)(v.w * rsv * nw.w);
    ((bf16x4*)(tn_bf + (size_t)row * D_))[t] = nb;
}

// ---------------------------------------------------------------------------
__global__ __launch_bounds__(256) void wgT_kernel(
    const float* __restrict__ wg, __bf16* __restrict__ wgT)
{
    const int g = blockIdx.x * 256 + threadIdx.x;
    const int h = g >> 10, d = g & 1023;
    wgT[g] = (h < 8) ? (__bf16)wg[d * 8 + h] : (__bf16)0.f;
}

// ---------------------------------------------------------------------------
// gates = sigmoid(tn @ wg) via MFMA: one wave per 16 rows, K=1024.
// ---------------------------------------------------------------------------
__global__ __launch_bounds__(256) void gates_kernel(
    const __bf16* __restrict__ tn, const __bf16* __restrict__ wgT,
    float* __restrict__ gates_out)
{
    const int w = threadIdx.x >> 6, lane = threadIdx.x & 63;
    const int fr = lane & 15, fq = lane >> 4;
    const int r0 = blockIdx.x * 64 + w * 16;
    const __bf16* arow = tn + (size_t)(r0 + fr) * D_ + fq * 8;
    const __bf16* brow = wgT + (size_t)fr * D_ + fq * 8;
    f32x4 acc = (f32x4){0.f, 0.f, 0.f, 0.f};
    #pragma unroll 8
    for (int k0 = 0; k0 < D_; k0 += 32) {
        bf16x8 a = *(const bf16x8*)(arow + k0);
        bf16x8 b = *(const bf16x8*)(brow + k0);
        acc = __builtin_amdgcn_mfma_f32_16x16x32_bf16(a, b, acc, 0, 0, 0);
    }
    if (fr < 8) {
        #pragma unroll
        for (int r = 0; r < 4; ++r)
            gates_out[(size_t)(r0 + fq * 4 + r) * H_ + fr] = 1.f / (1.f + expf(-acc[r]));
    }
}

// ---------------------------------------------------------------------------
__global__ __launch_bounds__(256) void convert_bf16_kernel(
    const float* __restrict__ in, __bf16* __restrict__ out)
{
    const int i = blockIdx.x * 256 + threadIdx.x;
    float4 v = ((const float4*)in)[i];
    bf16x4 o;
    o.x = (__bf16)v.x; o.y = (__bf16)v.y; o.z = (__bf16)v.z; o.w = (__bf16)v.w;
    *(bf16x4*)(out + (size_t)i * 4) = o;
}

// ---------------------------------------------------------------------------
__global__ __launch_bounds__(256) void transpose_convert_kernel(
    const float* __restrict__ in, __bf16* __restrict__ out, int R, int C)
{
    __shared__ float tile[32][33];
    const int bx = blockIdx.x;
    const int by = blockIdx.y;
    const int x = threadIdx.x & 31, y = threadIdx.x >> 5;
    #pragma unroll
    for (int r = 0; r < 4; ++r)
        tile[y + r * 8][x] = in[(size_t)(by * 32 + y + r * 8) * C + bx * 32 + x];
    __syncthreads();
    #pragma unroll
    for (int r = 0; r < 4; ++r)
        out[(size_t)(bx * 32 + y + r * 8) * R + by * 32 + x] = (__bf16)tile[x][y + r * 8];
}

// ---------------------------------------------------------------------------
// 256x256 phased bf16 MFMA GEMM, C = A @ Bt^T.  Pipelined phases: each
// phase's ds_reads are issued ONE PHASE BEFORE the MFMA that consumes them,
// so the LDS drain hides under the previous MFMA cluster + barrier.
// Buffer-hazard invariants from the verified R4 schedule are preserved:
//   - lgkmcnt(0) before any stage into As[p] (end of ph2)
//   - vmcnt(4) at tile end (A(t+2) left in flight), vmcnt(0) in tail
//   - sched_barrier(0) after every s_barrier
// MODE: 0 final (f32 out, K=512); 3 kv (A row-gather at 8192, bf16 out);
// 4 fused member+q.
// ---------------------------------------------------------------------------
template <int MODE>
__global__ __launch_bounds__(512, 2) void gemm_big(
    const __bf16* __restrict__ A, const __bf16* __restrict__ A2,
    const __bf16* __restrict__ Bt, const __bf16* __restrict__ Bt2,
    const float* __restrict__ bias,
    void* __restrict__ Cout, void* __restrict__ Cout2)
{
    __shared__ __align__(16) __bf16 As[2][256 * 64];   // 64 KiB
    __shared__ __align__(16) __bf16 Bs[2][256 * 64];   // 64 KiB

    constexpr int NT = (MODE == 0) ? 8 : 16;           // K = NT*64
    constexpr int K = NT * 64;

    const int tid = threadIdx.x;
    const int w = tid >> 6, lane = tid & 63;
    const int wm = w >> 2, wn = w & 3;
    const int fr = lane & 15, fq = lane >> 4;

    const int bid = blockIdx.x;
    int m0, n0, Ncols;
    const __bf16 *Ab, *Btb;
    const float* biasp = nullptr;
    void* Co;

    if (MODE == 4) {
        const bool isq = bid >= 128;
        const int b2 = isq ? bid - 128 : bid;
        const int ntx = isq ? 2 : 4;
        const int c = b2 & 7, s = b2 >> 3;
        const int sq = s / ntx;
        m0 = (c * 4 + sq) * 256;
        n0 = (s - sq * ntx) * 256;
        if (isq) {
            Ab = A2 + (size_t)m0 * K; Btb = Bt2 + (size_t)n0 * K;
            Co = Cout2; Ncols = 512;
        } else {
            Ab = A + (size_t)m0 * K;
            Btb = Bt + (size_t)(m0 >> 10) * 1024 * K + (size_t)n0 * K;
            Co = Cout; Ncols = 1024;
            biasp = bias + (size_t)(m0 >> 10) * 1024;
        }
    } else {
        const int ntx = 4;
        const int nty8 = (MODE == 3) ? 8 : 4;
        const int c = bid & 7, s = bid >> 3;
        const int sq = s / ntx;
        m0 = (c * nty8 + sq) * 256;
        n0 = (s - sq * ntx) * 256;
        Ncols = 1024;
        Co = Cout;
        if (MODE == 3)
            Ab = (m0 >= 8192) ? (A2 + (size_t)(m0 - 8192) * K) : (A + (size_t)m0 * K);
        else
            Ab = A + (size_t)m0 * K;
        Btb = Bt + (size_t)n0 * K;
    }

    // staging lane constants (T2 swizzle via pre-swizzled global source)
    const int lrow = lane >> 3;
    const int lchunk = (lane & 7) ^ lrow;
    const int fo0 = ((fq ^ (lane & 7)) << 4);
    const int fo1 = (((4 + fq) ^ (lane & 7)) << 4);

#define STAGE_A(T2, PB, HALF) do {                                            \
    _Pragma("unroll")                                                         \
    for (int ld = (HALF) * 2; ld < (HALF) * 2 + 2; ++ld)                      \
        GLL(Ab + (size_t)(w * 32 + ld * 8 + lrow) * K + (T2) * 64 + lchunk * 8, \
            &As[PB][(w * 32 + ld * 8) * 64]);                                 \
} while (0)
#define STAGE_B(T2, PB, HALF) do {                                            \
    _Pragma("unroll")                                                         \
    for (int ld = (HALF) * 2; ld < (HALF) * 2 + 2; ++ld)                      \
        GLL(Btb + (size_t)(w * 32 + ld * 8 + lrow) * K + (T2) * 64 + lchunk * 8, \
            &Bs[PB][(w * 32 + ld * 8) * 64]);                                 \
} while (0)
#define RD_A(DST, MIOFF, FO) do {                                             \
    _Pragma("unroll")                                                         \
    for (int mi = 0; mi < 4; ++mi)                                            \
        (DST)[mi] = *(const bf16x8*)(Ap + ((wm * 128 + ((MIOFF) + mi) * 16 + fr) << 7) + (FO)); \
} while (0)
#define RD_B(DST, FO) do {                                                    \
    _Pragma("unroll")                                                         \
    for (int nj = 0; nj < 4; ++nj)                                            \
        (DST)[nj] = *(const bf16x8*)(Bp + ((wn * 64 + nj * 16 + fr) << 7) + (FO)); \
} while (0)
#define MFMA4(AFR, BFR, AOFF) do {                                            \
    _Pragma("unroll")                                                         \
    for (int mi = 0; mi < 4; ++mi)                                            \
        _Pragma("unroll")                                                     \
        for (int nj = 0; nj < 4; ++nj)                                        \
            acc[(AOFF) + mi][nj] = __builtin_amdgcn_mfma_f32_16x16x32_bf16(   \
                (AFR)[mi], (BFR)[nj], acc[(AOFF) + mi][nj], 0, 0, 0);         \
} while (0)

    f32x4 acc[8][4];
    #pragma unroll
    for (int mi = 0; mi < 8; ++mi)
        #pragma unroll
        for (int nj = 0; nj < 4; ++nj)
            acc[mi][nj] = (f32x4){0.f, 0.f, 0.f, 0.f};

    // prologue: tile0 A+B, tile1 A.  drain tile0, leave tile1-A in flight.
    STAGE_A(0, 0, 0); STAGE_A(0, 0, 1);
    STAGE_B(0, 0, 0); STAGE_B(0, 0, 1);
    STAGE_A(1, 1, 0); STAGE_A(1, 1, 1);
    asm volatile("s_waitcnt vmcnt(4)" ::: "memory");
    BARF();

    for (int t = 0; t < NT; ++t) {
        const int p = t & 1;
        const char* Ap = (const char*)&As[p][0];
        const char* Bp = (const char*)&Bs[p][0];
        bf16x8 a0[4], a1[4], a2[4], a3[4], b0[4], b1[4];

        // head: read ph1's frags (a0,b0); stage B(t+1)h0
        RD_A(a0, 0, fo0); RD_B(b0, fo0);
        if (t + 1 < NT) STAGE_B(t + 1, p ^ 1, 0);
        BARF();

        // ph1: read a1 (for ph2); stage B(t+1)h1; MFMA a0xb0 (lgkm counted)
        RD_A(a1, 4, fo0);
        if (t + 1 < NT) STAGE_B(t + 1, p ^ 1, 1);
        __builtin_amdgcn_s_setprio(1);
        MFMA4(a0, b0, 0);
        __builtin_amdgcn_s_setprio(0);
        BARF();

        // ph2: read a2,b1,a3 (for ph3/4); MFMA a1xb0; drain all LDS reads
        // (required before ph3 overwrites As[p])
        RD_A(a2, 0, fo1); RD_B(b1, fo1); RD_A(a3, 4, fo1);
        __builtin_amdgcn_s_setprio(1);
        MFMA4(a1, b0, 4);
        __builtin_amdgcn_s_setprio(0);
        asm volatile("s_waitcnt lgkmcnt(0)" ::: "memory");
        BARF();

        // ph3: stage A(t+2)h0 into As[p] (all reads done); MFMA a2xb1
        if (t + 2 < NT) STAGE_A(t + 2, p, 0);
        __builtin_amdgcn_s_setprio(1);
        MFMA4(a2, b1, 0);
        __builtin_amdgcn_s_setprio(0);
        BARF();

        // ph4: stage A(t+2)h1; MFMA a3xb1; counted vmcnt; tile-end barrier
        if (t + 2 < NT) STAGE_A(t + 2, p, 1);
        __builtin_amdgcn_s_setprio(1);
        MFMA4(a3, b1, 4);
        __builtin_amdgcn_s_setprio(0);
        if (t + 2 < NT) { asm volatile("s_waitcnt vmcnt(4)" ::: "memory"); }
        else            { asm volatile("s_waitcnt vmcnt(0)" ::: "memory"); }
        BARF();
    }

    // epilogue: D mapping col=lane&15, row=(lane>>4)*4+reg
    #pragma unroll
    for (int mi = 0; mi < 8; ++mi) {
        const int r0 = m0 + wm * 128 + mi * 16 + fq * 4;
        #pragma unroll
        for (int nj = 0; nj < 4; ++nj) {
            const int col = n0 + wn * 64 + nj * 16 + fr;
            const float badd = (MODE == 4 && biasp != nullptr) ? biasp[col] : 0.f;
            #pragma unroll
            for (int r = 0; r < 4; ++r) {
                float v = acc[mi][nj][r] + badd;
                if (MODE == 0)
                    ((float*)Co)[(size_t)(r0 + r) * Ncols + col] = v;
                else
                    ((__bf16*)Co)[(size_t)(r0 + r) * Ncols + col] = (__bf16)v;
            }
        }
    }
#undef STAGE_A
#undef STAGE_B
#undef RD_A
#undef RD_B
#undef MFMA4
}

// ---------------------------------------------------------------------------
// Merged-heads attention: one 512-thread block per (b,n) site; wave = head.
// Coalesced full-row loads into LDS; xor-shuffle softmax (no serial section);
// kscale computed redundantly per-lane (no LDS round-trip).
// ---------------------------------------------------------------------------
__global__ __launch_bounds__(512) void attn_kernel(
    const __bf16* __restrict__ q,     // [8192, 512]
    const __bf16* __restrict__ kv,    // [16384, 1024]  (k | v)
    const float* __restrict__ gates,  // [8192, 8]
    const float* __restrict__ knw,    // [64]
    __bf16* __restrict__ og)          // [8192, 512]
{
    const int bn = blockIdx.x;        // 0..1023
    const int tid = threadIdx.x;
    const int h = tid >> 6, lane = tid & 63;

    __shared__ __align__(16) __bf16 qs[8][520];
    __shared__ __align__(16) __bf16 kvs[16][1032];
    __shared__ float ssm[8][8][17];   // [h][l][m] attn weights
    __shared__ float kn[64];
    __shared__ float gs[64];          // [l*8+h]

    // coalesced loads
    {
        const int l = tid >> 6, c8 = tid & 63;
        *(bf16x8*)&qs[l][c8 * 8] =
            *(const bf16x8*)(q + ((size_t)(l * BN_TOK + bn)) * INNER_ + c8 * 8);
    }
    #pragma unroll
    for (int i = 0; i < 4; ++i) {
        const int g = tid + i * 512;
        const int m = g >> 7, c8 = g & 127;
        *(bf16x8*)&kvs[m][c8 * 8] =
            *(const bf16x8*)(kv + ((size_t)(m * BN_TOK + bn)) * 1024 + c8 * 8);
    }
    if (tid < 64) {
        kn[tid] = knw[tid];
        gs[tid] = gates[((size_t)((tid >> 3) * BN_TOK + bn)) * H_ + (tid & 7)];
    }
    __syncthreads();

    // ---- per-wave (head h) from here; no cross-wave LDS writes below.
    const int m = lane & 15, grp = lane >> 4;

    // k RMS scale for this lane's m (redundant across the 4 grp lanes)
    float s2 = 0.f;
    #pragma unroll
    for (int j = 0; j < 16; ++j) {
        float v = (float)kvs[m][h * DH_ + grp * 16 + j];
        s2 = fmaf(v, v, s2);
    }
    s2 += __shfl_xor(s2, 16);
    s2 += __shfl_xor(s2, 32);
    const float kscale = rsqrtf(s2 * (1.f / DH_) + EPS) * SCALE_;

    // sims: lane -> (l = grp, m) and (l = grp+4, m)
    const int l0 = grp, l1 = grp + 4;
    float sim0 = 0.f, sim1 = 0.f;
    #pragma unroll
    for (int d = 0; d < DH_; ++d) {
        const float kf = (float)kvs[m][h * DH_ + d] * kn[d];
        sim0 = fmaf((float)qs[l0][h * DH_ + d], kf, sim0);
        sim1 = fmaf((float)qs[l1][h * DH_ + d], kf, sim1);
    }
    sim0 *= kscale; sim1 *= kscale;

    // softmax over m via xor-shuffles within 16-lane groups
    float mx0 = sim0, mx1 = sim1;
    #pragma unroll
    for (int o = 1; o < 16; o <<= 1) {
        mx0 = fmaxf(mx0, __shfl_xor(mx0, o));
        mx1 = fmaxf(mx1, __shfl_xor(mx1, o));
    }
    float e0 = expf(sim0 - mx0), e1 = expf(sim1 - mx1);
    float sm0 = e0, sm1 = e1;
    #pragma unroll
    for (int o = 1; o < 16; o <<= 1) {
        sm0 += __shfl_xor(sm0, o);
        sm1 += __shfl_xor(sm1, o);
    }
    ssm[h][l0][m] = e0 / sm0;
    ssm[h][l1][m] = e1 / sm1;
    // wave-internal LDS write->read; compiler inserts lgkm wait (same wave)

    // PV: lane owns output dim d = lane for all 8 l
    float vf[16];
    #pragma unroll
    for (int mm = 0; mm < 16; ++mm)
        vf[mm] = (float)kvs[mm][INNER_ + h * DH_ + lane];
    #pragma unroll
    for (int l = 0; l < 8; ++l) {
        float o = 0.f;
        #pragma unroll
        for (int mm = 0; mm < 16; ++mm) o = fmaf(ssm[h][l][mm], vf[mm], o);
        og[((size_t)(l * BN_TOK + bn)) * INNER_ + h * DH_ + lane] =
            (__bf16)(o * gs[l * 8 + h]);
    }
}

// ---------------------------------------------------------------------------
extern "C" void kernel_launch(void* const* d_in, const int* in_sizes, int n_in,
                              void* d_out, int out_size, void* d_ws, size_t ws_size,
                              hipStream_t stream)
{
    const float* tokens = (const float*)d_in[0];  // [8,2,512,1024]
    const float* w_net  = (const float*)d_in[1];  // [8,1024,1024]
    const float* b_net  = (const float*)d_in[2];  // [8,1024]
    const float* norm_w = (const float*)d_in[3];  // [1024]
    const float* wq     = (const float*)d_in[4];  // [1024,512]
    const float* wkv    = (const float*)d_in[5];  // [1024,1024]
    const float* knw    = (const float*)d_in[6];  // [64]
    const float* wg     = (const float*)d_in[7];  // [1024,8]
    const float* wout   = (const float*)d_in[8];  // [512,1024]
    float* out = (float*)d_out;                   // [8,2,512,1024]

    char* ws = (char*)d_ws;
    __bf16* tok_bf  = (__bf16*)(ws);                         // 16,777,216 B
    __bf16* tn_bf   = (__bf16*)(ws + 16777216);              // 16,777,216
    __bf16* out_bf  = (__bf16*)(ws + 33554432);              // 16,777,216
    __bf16* q_bf    = (__bf16*)(ws + 50331648);              //  8,388,608
    __bf16* kv_bf   = (__bf16*)(ws + 58720256);              // 33,554,432
    __bf16* og_bf   = (__bf16*)(ws + 92274688);              //  8,388,608
    __bf16* wnet_bf = (__bf16*)(ws + 100663296);             // 16,777,216
    __bf16* wqt_bf  = (__bf16*)(ws + 117440512);             //  1,048,576
    __bf16* wkvt_bf = (__bf16*)(ws + 118489088);             //  2,097,152
    __bf16* woutt_bf= (__bf16*)(ws + 120586240);             //  1,048,576
    float*  ws_g    = (float*)(ws + 121667584);              //    262,144
    __bf16* wgT_bf  = (__bf16*)(ws + 121929728);             //     32,768

    rs_kernel<<<L_ * BN_TOK, 256, 0, stream>>>(tokens, norm_w, tok_bf, tn_bf);
    convert_bf16_kernel<<<8192, 256, 0, stream>>>(w_net, wnet_bf);
    transpose_convert_kernel<<<dim3(16, 32), 256, 0, stream>>>(wq, wqt_bf, 1024, 512);
    transpose_convert_kernel<<<dim3(32, 32), 256, 0, stream>>>(wkv, wkvt_bf, 1024, 1024);
    transpose_convert_kernel<<<dim3(32, 16), 256, 0, stream>>>(wout, woutt_bf, 512, 1024);
    wgT_kernel<<<64, 256, 0, stream>>>(wg, wgT_bf);

    gates_kernel<<<128, 256, 0, stream>>>(tn_bf, wgT_bf, ws_g);

    // fused member linear + q projection (192 blocks)
    gemm_big<4><<<192, 512, 0, stream>>>(tok_bf, tn_bf, wnet_bf, wqt_bf, b_net,
                                         (void*)out_bf, (void*)q_bf);
    // kv = ctx @ wkv  (256 blocks)
    gemm_big<3><<<256, 512, 0, stream>>>(tok_bf, out_bf, wkvt_bf, nullptr, nullptr,
                                         (void*)kv_bf, nullptr);
    // attention + gating (merged heads)
    attn_kernel<<<BN_TOK, 512, 0, stream>>>(q_bf, kv_bf, ws_g, knw, og_bf);
    // pooled = og @ wout -> d_out (f32)
    gemm_big<0><<<128, 512, 0, stream>>>(og_bf, nullptr, woutt_bf, nullptr, nullptr,
                                         (void*)out, nullptr);
}

// Round 7
// 148.938 us; speedup vs baseline: 1.3495x; 1.0077x over previous
//
#include <hip/hip_runtime.h>
#include <hip/hip_bf16.h>
#include <math.h>

#define L_ 8
#define B_ 2
#define N_ 512
#define D_ 1024
#define H_ 8
#define DH_ 64
#define INNER_ 512
#define M_ 16
#define BN_TOK 1024            // B_*N_
#define EPS 1.1920928955078125e-07f
#define SCALE_ 0.125f          // DH^-0.5

typedef __attribute__((ext_vector_type(8))) __bf16 bf16x8;
typedef __attribute__((ext_vector_type(4))) __bf16 bf16x4;
typedef __attribute__((ext_vector_type(4))) float f32x4;

#define BARF() do { __builtin_amdgcn_s_barrier(); __builtin_amdgcn_sched_barrier(0); } while (0)
#define LGKM(N) do { asm volatile("s_waitcnt lgkmcnt(" #N ")" ::: "memory"); \
                     __builtin_amdgcn_sched_barrier(0); } while (0)
#define GLL(SRC, DST) __builtin_amdgcn_global_load_lds( \
    (const __attribute__((address_space(1))) void*)(SRC), \
    (__attribute__((address_space(3))) void*)(DST), 16, 0, 0)

// ---------------------------------------------------------------------------
// Streaming rms + bf16 convert: one 256-thread block per (l,b,n) row.
// ---------------------------------------------------------------------------
__global__ __launch_bounds__(256) void rs_kernel(
    const float* __restrict__ tokens, const float* __restrict__ norm_w,
    __bf16* __restrict__ tok_bf, __bf16* __restrict__ tn_bf)
{
    const int row = blockIdx.x;
    const int t = threadIdx.x;
    const int wave = t >> 6, lane = t & 63;
    __shared__ float wsum[4];

    const float4 v = ((const float4*)(tokens + (size_t)row * D_))[t];
    float ss = fmaf(v.x, v.x, fmaf(v.y, v.y, fmaf(v.z, v.z, v.w * v.w)));
    #pragma unroll
    for (int o = 1; o < 64; o <<= 1) ss += __shfl_xor(ss, o);
    if (lane == 0) wsum[wave] = ss;
    __syncthreads();
    const float rsv = rsqrtf((wsum[0] + wsum[1] + wsum[2] + wsum[3]) * (1.f / D_) + EPS);

    const float4 nw = ((const float4*)norm_w)[t];
    bf16x4 tb; tb.x = (__bf16)v.x; tb.y = (__bf16)v.y; tb.z = (__bf16)v.z; tb.w = (__bf16)v.w;
    ((bf16x4*)(tok_bf + (size_t)row * D_))[t] = tb;
    bf16x4 nb;
    nb.x = (__bf16)(v.x * rsv * nw.x); nb.y = (__bf16)(v.y * rsv * nw.y);
    nb.z = (__bf16)(v.z * rsv * nw.z); nb.w = (__bf16)(v.w * rsv * nw.w);
    ((bf16x4*)(tn_bf + (size_t)row * D_))[t] = nb;
}

// ---------------------------------------------------------------------------
__global__ __launch_bounds__(256) void wgT_kernel(
    const float* __restrict__ wg, __bf16* __restrict__ wgT)
{
    const int g = blockIdx.x * 256 + threadIdx.x;
    const int h = g >> 10, d = g & 1023;
    wgT[g] = (h < 8) ? (__bf16)wg[d * 8 + h] : (__bf16)0.f;
}

// ---------------------------------------------------------------------------
// gates = sigmoid(tn @ wg) via MFMA: one wave per 16 rows, K=1024.
// ---------------------------------------------------------------------------
__global__ __launch_bounds__(256) void gates_kernel(
    const __bf16* __restrict__ tn, const __bf16* __restrict__ wgT,
    float* __restrict__ gates_out)
{
    const int w = threadIdx.x >> 6, lane = threadIdx.x & 63;
    const int fr = lane & 15, fq = lane >> 4;
    const int r0 = blockIdx.x * 64 + w * 16;
    const __bf16* arow = tn + (size_t)(r0 + fr) * D_ + fq * 8;
    const __bf16* brow = wgT + (size_t)fr * D_ + fq * 8;
    f32x4 acc = (f32x4){0.f, 0.f, 0.f, 0.f};
    #pragma unroll 8
    for (int k0 = 0; k0 < D_; k0 += 32) {
        bf16x8 a = *(const bf16x8*)(arow + k0);
        bf16x8 b = *(const bf16x8*)(brow + k0);
        acc = __builtin_amdgcn_mfma_f32_16x16x32_bf16(a, b, acc, 0, 0, 0);
    }
    if (fr < 8) {
        #pragma unroll
        for (int r = 0; r < 4; ++r)
            gates_out[(size_t)(r0 + fq * 4 + r) * H_ + fr] = 1.f / (1.f + expf(-acc[r]));
    }
}

// ---------------------------------------------------------------------------
__global__ __launch_bounds__(256) void convert_bf16_kernel(
    const float* __restrict__ in, __bf16* __restrict__ out)
{
    const int i = blockIdx.x * 256 + threadIdx.x;
    float4 v = ((const float4*)in)[i];
    bf16x4 o;
    o.x = (__bf16)v.x; o.y = (__bf16)v.y; o.z = (__bf16)v.z; o.w = (__bf16)v.w;
    *(bf16x4*)(out + (size_t)i * 4) = o;
}

// ---------------------------------------------------------------------------
__global__ __launch_bounds__(256) void transpose_convert_kernel(
    const float* __restrict__ in, __bf16* __restrict__ out, int R, int C)
{
    __shared__ float tile[32][33];
    const int bx = blockIdx.x;
    const int by = blockIdx.y;
    const int x = threadIdx.x & 31, y = threadIdx.x >> 5;
    #pragma unroll
    for (int r = 0; r < 4; ++r)
        tile[y + r * 8][x] = in[(size_t)(by * 32 + y + r * 8) * C + bx * 32 + x];
    __syncthreads();
    #pragma unroll
    for (int r = 0; r < 4; ++r)
        out[(size_t)(bx * 32 + y + r * 8) * R + by * 32 + x] = (__bf16)tile[x][y + r * 8];
}

// ---------------------------------------------------------------------------
// 256x256 bf16 MFMA GEMM, C = A @ Bt^T.  BK=64, 512 thr = 8 waves (2m x 4n),
// wave tile 128x64.  Counted-lgkm pipeline: reads front-loaded [12,12,0,0]
// across 4 phases with counted lgkm waits (4/12/4/0) so ds_reads drain
// DURING the MFMA clusters instead of before them.  Hazards:
//  - A[p] reads all issued by ph1; A(t+2) staged ph2/ph3 (DMA returns >=180cy
//    after issue, >=1 phase after the reads' bank access; ph1-close barrier
//    orders all waves' read-issue before ph2 stage-issue).
//  - B[p^1] staged ph0/ph1 was last read one full tile earlier.
//  - vmcnt(4) at tile end: FIFO retire => A(t+1)/B(t+1) landed, A(t+2) in
//    flight.  Tail (t+2>=NT): vmcnt(0) since outstanding then includes
//    needed B halves.
// MODE: 0 final (f32 out, K=512); 3 kv (A row-gather at 8192); 4 member+q.
// ---------------------------------------------------------------------------
template <int MODE>
__global__ __launch_bounds__(512, 2) void gemm_big(
    const __bf16* __restrict__ A, const __bf16* __restrict__ A2,
    const __bf16* __restrict__ Bt, const __bf16* __restrict__ Bt2,
    const float* __restrict__ bias,
    void* __restrict__ Cout, void* __restrict__ Cout2)
{
    __shared__ __align__(16) __bf16 As[2][256 * 64];   // 64 KiB
    __shared__ __align__(16) __bf16 Bs[2][256 * 64];   // 64 KiB

    constexpr int NT = (MODE == 0) ? 8 : 16;           // K = NT*64
    constexpr int K = NT * 64;

    const int tid = threadIdx.x;
    const int w = tid >> 6, lane = tid & 63;
    const int wm = w >> 2, wn = w & 3;
    const int fr = lane & 15, fq = lane >> 4;

    const int bid = blockIdx.x;
    int m0, n0, Ncols;
    const __bf16 *Ab, *Btb;
    const float* biasp = nullptr;
    void* Co;

    if (MODE == 4) {
        const bool isq = bid >= 128;
        const int b2 = isq ? bid - 128 : bid;
        const int ntx = isq ? 2 : 4;
        const int c = b2 & 7, s = b2 >> 3;
        const int sq = s / ntx;
        m0 = (c * 4 + sq) * 256;
        n0 = (s - sq * ntx) * 256;
        if (isq) {
            Ab = A2 + (size_t)m0 * K; Btb = Bt2 + (size_t)n0 * K;
            Co = Cout2; Ncols = 512;
        } else {
            Ab = A + (size_t)m0 * K;
            Btb = Bt + (size_t)(m0 >> 10) * 1024 * K + (size_t)n0 * K;
            Co = Cout; Ncols = 1024;
            biasp = bias + (size_t)(m0 >> 10) * 1024;
        }
    } else {
        const int ntx = 4;
        const int nty8 = (MODE == 3) ? 8 : 4;
        const int c = bid & 7, s = bid >> 3;
        const int sq = s / ntx;
        m0 = (c * nty8 + sq) * 256;
        n0 = (s - sq * ntx) * 256;
        Ncols = 1024;
        Co = Cout;
        if (MODE == 3)
            Ab = (m0 >= 8192) ? (A2 + (size_t)(m0 - 8192) * K) : (A + (size_t)m0 * K);
        else
            Ab = A + (size_t)m0 * K;
        Btb = Bt + (size_t)n0 * K;
    }

    // staging lane constants (T2 swizzle via pre-swizzled global source)
    const int lrow = lane >> 3;
    const int lchunk = (lane & 7) ^ lrow;
    const int fo0 = ((fq ^ (lane & 7)) << 4);
    const int fo1 = (((4 + fq) ^ (lane & 7)) << 4);

#define STAGE_A(T2, PB, HALF) do {                                            \
    _Pragma("unroll")                                                         \
    for (int ld = (HALF) * 2; ld < (HALF) * 2 + 2; ++ld)                      \
        GLL(Ab + (size_t)(w * 32 + ld * 8 + lrow) * K + (T2) * 64 + lchunk * 8, \
            &As[PB][(w * 32 + ld * 8) * 64]);                                 \
} while (0)
#define STAGE_B(T2, PB, HALF) do {                                            \
    _Pragma("unroll")                                                         \
    for (int ld = (HALF) * 2; ld < (HALF) * 2 + 2; ++ld)                      \
        GLL(Btb + (size_t)(w * 32 + ld * 8 + lrow) * K + (T2) * 64 + lchunk * 8, \
            &Bs[PB][(w * 32 + ld * 8) * 64]);                                 \
} while (0)
#define RD_A(DST, MIOFF, FO) do {                                             \
    _Pragma("unroll")                                                         \
    for (int mi = 0; mi < 4; ++mi)                                            \
        (DST)[mi] = *(const bf16x8*)(Ap + ((wm * 128 + ((MIOFF) + mi) * 16 + fr) << 7) + (FO)); \
} while (0)
#define RD_B(DST, FO) do {                                                    \
    _Pragma("unroll")                                                         \
    for (int nj = 0; nj < 4; ++nj)                                            \
        (DST)[nj] = *(const bf16x8*)(Bp + ((wn * 64 + nj * 16 + fr) << 7) + (FO)); \
} while (0)
#define MFMA4(AFR, BFR, AOFF) do {                                            \
    _Pragma("unroll")                                                         \
    for (int mi = 0; mi < 4; ++mi)                                            \
        _Pragma("unroll")                                                     \
        for (int nj = 0; nj < 4; ++nj)                                        \
            acc[(AOFF) + mi][nj] = __builtin_amdgcn_mfma_f32_16x16x32_bf16(   \
                (AFR)[mi], (BFR)[nj], acc[(AOFF) + mi][nj], 0, 0, 0);         \
} while (0)

    f32x4 acc[8][4];
    #pragma unroll
    for (int mi = 0; mi < 8; ++mi)
        #pragma unroll
        for (int nj = 0; nj < 4; ++nj)
            acc[mi][nj] = (f32x4){0.f, 0.f, 0.f, 0.f};

    // prologue: A(0), B(0), A(1).  vmcnt(4): A0,B0 landed; A1 in flight.
    STAGE_A(0, 0, 0); STAGE_A(0, 0, 1);
    STAGE_B(0, 0, 0); STAGE_B(0, 0, 1);
    STAGE_A(1, 1, 0); STAGE_A(1, 1, 1);
    asm volatile("s_waitcnt vmcnt(4)" ::: "memory");
    BARF();

    for (int t = 0; t < NT; ++t) {
        const int p = t & 1;
        const char* Ap = (const char*)&As[p][0];
        const char* Bp = (const char*)&Bs[p][0];
        bf16x8 am0k0[4], am1k0[4], bk0[4], am0k1[4], am1k1[4], bk1[4];

        // ph0: 12 reads [Am0k0, Bk0, Am1k0]; stage B(t+1)h0
        RD_A(am0k0, 0, fo0); RD_B(bk0, fo0); RD_A(am1k0, 4, fo0);
        if (t + 1 < NT) STAGE_B(t + 1, p ^ 1, 0);
        BARF();
        LGKM(4);                           // Am0k0+Bk0 done; Am1k0 in flight
        __builtin_amdgcn_s_setprio(1);
        MFMA4(am0k0, bk0, 0);
        __builtin_amdgcn_s_setprio(0);
        BARF();

        // ph1: 12 reads [Am0k1, Bk1, Am1k1]; stage B(t+1)h1
        RD_A(am0k1, 0, fo1); RD_B(bk1, fo1); RD_A(am1k1, 4, fo1);
        if (t + 1 < NT) STAGE_B(t + 1, p ^ 1, 1);
        BARF();
        LGKM(12);                          // drains Am1k0; ph1's 12 in flight
        __builtin_amdgcn_s_setprio(1);
        MFMA4(am1k0, bk0, 4);
        __builtin_amdgcn_s_setprio(0);
        BARF();

        // ph2: stage A(t+2)h0 into As[p] (all A[p] reads issued by ph1)
        if (t + 2 < NT) STAGE_A(t + 2, p, 0);
        LGKM(4);                           // Am0k1+Bk1 done; Am1k1 in flight
        __builtin_amdgcn_s_setprio(1);
        MFMA4(am0k1, bk1, 0);
        __builtin_amdgcn_s_setprio(0);
        BARF();

        // ph3: stage A(t+2)h1; drain reads; counted vmcnt; tile-end barrier
        if (t + 2 < NT) STAGE_A(t + 2, p, 1);
        LGKM(0);
        __builtin_amdgcn_s_setprio(1);
        MFMA4(am1k1, bk1, 4);
        __builtin_amdgcn_s_setprio(0);
        if (t + 2 < NT) { asm volatile("s_waitcnt vmcnt(4)" ::: "memory"); }
        else            { asm volatile("s_waitcnt vmcnt(0)" ::: "memory"); }
        BARF();
    }

    // epilogue: D mapping col=lane&15, row=(lane>>4)*4+reg
    #pragma unroll
    for (int mi = 0; mi < 8; ++mi) {
        const int r0 = m0 + wm * 128 + mi * 16 + fq * 4;
        #pragma unroll
        for (int nj = 0; nj < 4; ++nj) {
            const int col = n0 + wn * 64 + nj * 16 + fr;
            const float badd = (MODE == 4 && biasp != nullptr) ? biasp[col] : 0.f;
            #pragma unroll
            for (int r = 0; r < 4; ++r) {
                float v = acc[mi][nj][r] + badd;
                if (MODE == 0)
                    ((float*)Co)[(size_t)(r0 + r) * Ncols + col] = v;
                else
                    ((__bf16*)Co)[(size_t)(r0 + r) * Ncols + col] = (__bf16)v;
            }
        }
    }
#undef STAGE_A
#undef STAGE_B
#undef RD_A
#undef RD_B
#undef MFMA4
}

// ---------------------------------------------------------------------------
// Merged-heads attention: one 512-thread block per (b,n) site; wave = head.
// ---------------------------------------------------------------------------
__global__ __launch_bounds__(512) void attn_kernel(
    const __bf16* __restrict__ q,     // [8192, 512]
    const __bf16* __restrict__ kv,    // [16384, 1024]  (k | v)
    const float* __restrict__ gates,  // [8192, 8]
    const float* __restrict__ knw,    // [64]
    __bf16* __restrict__ og)          // [8192, 512]
{
    const int bn = blockIdx.x;        // 0..1023
    const int tid = threadIdx.x;
    const int h = tid >> 6, lane = tid & 63;

    __shared__ __align__(16) __bf16 qs[8][520];
    __shared__ __align__(16) __bf16 kvs[16][1032];
    __shared__ float ssm[8][8][17];   // [h][l][m] attn weights
    __shared__ float kn[64];
    __shared__ float gs[64];          // [l*8+h]

    {
        const int l = tid >> 6, c8 = tid & 63;
        *(bf16x8*)&qs[l][c8 * 8] =
            *(const bf16x8*)(q + ((size_t)(l * BN_TOK + bn)) * INNER_ + c8 * 8);
    }
    #pragma unroll
    for (int i = 0; i < 4; ++i) {
        const int g = tid + i * 512;
        const int m = g >> 7, c8 = g & 127;
        *(bf16x8*)&kvs[m][c8 * 8] =
            *(const bf16x8*)(kv + ((size_t)(m * BN_TOK + bn)) * 1024 + c8 * 8);
    }
    if (tid < 64) {
        kn[tid] = knw[tid];
        gs[tid] = gates[((size_t)((tid >> 3) * BN_TOK + bn)) * H_ + (tid & 7)];
    }
    __syncthreads();

    const int m = lane & 15, grp = lane >> 4;

    float s2 = 0.f;
    #pragma unroll
    for (int j = 0; j < 16; ++j) {
        float v = (float)kvs[m][h * DH_ + grp * 16 + j];
        s2 = fmaf(v, v, s2);
    }
    s2 += __shfl_xor(s2, 16);
    s2 += __shfl_xor(s2, 32);
    const float kscale = rsqrtf(s2 * (1.f / DH_) + EPS) * SCALE_;

    const int l0 = grp, l1 = grp + 4;
    float sim0 = 0.f, sim1 = 0.f;
    #pragma unroll
    for (int d = 0; d < DH_; ++d) {
        const float kf = (float)kvs[m][h * DH_ + d] * kn[d];
        sim0 = fmaf((float)qs[l0][h * DH_ + d], kf, sim0);
        sim1 = fmaf((float)qs[l1][h * DH_ + d], kf, sim1);
    }
    sim0 *= kscale; sim1 *= kscale;

    float mx0 = sim0, mx1 = sim1;
    #pragma unroll
    for (int o = 1; o < 16; o <<= 1) {
        mx0 = fmaxf(mx0, __shfl_xor(mx0, o));
        mx1 = fmaxf(mx1, __shfl_xor(mx1, o));
    }
    float e0 = expf(sim0 - mx0), e1 = expf(sim1 - mx1);
    float sm0 = e0, sm1 = e1;
    #pragma unroll
    for (int o = 1; o < 16; o <<= 1) {
        sm0 += __shfl_xor(sm0, o);
        sm1 += __shfl_xor(sm1, o);
    }
    ssm[h][l0][m] = e0 / sm0;
    ssm[h][l1][m] = e1 / sm1;

    float vf[16];
    #pragma unroll
    for (int mm = 0; mm < 16; ++mm)
        vf[mm] = (float)kvs[mm][INNER_ + h * DH_ + lane];
    #pragma unroll
    for (int l = 0; l < 8; ++l) {
        float o = 0.f;
        #pragma unroll
        for (int mm = 0; mm < 16; ++mm) o = fmaf(ssm[h][l][mm], vf[mm], o);
        og[((size_t)(l * BN_TOK + bn)) * INNER_ + h * DH_ + lane] =
            (__bf16)(o * gs[l * 8 + h]);
    }
}

// ---------------------------------------------------------------------------
extern "C" void kernel_launch(void* const* d_in, const int* in_sizes, int n_in,
                              void* d_out, int out_size, void* d_ws, size_t ws_size,
                              hipStream_t stream)
{
    const float* tokens = (const float*)d_in[0];  // [8,2,512,1024]
    const float* w_net  = (const float*)d_in[1];  // [8,1024,1024]
    const float* b_net  = (const float*)d_in[2];  // [8,1024]
    const float* norm_w = (const float*)d_in[3];  // [1024]
    const float* wq     = (const float*)d_in[4];  // [1024,512]
    const float* wkv    = (const float*)d_in[5];  // [1024,1024]
    const float* knw    = (const float*)d_in[6];  // [64]
    const float* wg     = (const float*)d_in[7];  // [1024,8]
    const float* wout   = (const float*)d_in[8];  // [512,1024]
    float* out = (float*)d_out;                   // [8,2,512,1024]

    char* ws = (char*)d_ws;
    __bf16* tok_bf  = (__bf16*)(ws);                         // 16,777,216 B
    __bf16* tn_bf   = (__bf16*)(ws + 16777216);              // 16,777,216
    __bf16* out_bf  = (__bf16*)(ws + 33554432);              // 16,777,216
    __bf16* q_bf    = (__bf16*)(ws + 50331648);              //  8,388,608
    __bf16* kv_bf   = (__bf16*)(ws + 58720256);              // 33,554,432
    __bf16* og_bf   = (__bf16*)(ws + 92274688);              //  8,388,608
    __bf16* wnet_bf = (__bf16*)(ws + 100663296);             // 16,777,216
    __bf16* wqt_bf  = (__bf16*)(ws + 117440512);             //  1,048,576
    __bf16* wkvt_bf = (__bf16*)(ws + 118489088);             //  2,097,152
    __bf16* woutt_bf= (__bf16*)(ws + 120586240);             //  1,048,576
    float*  ws_g    = (float*)(ws + 121667584);              //    262,144
    __bf16* wgT_bf  = (__bf16*)(ws + 121929728);             //     32,768

    rs_kernel<<<L_ * BN_TOK, 256, 0, stream>>>(tokens, norm_w, tok_bf, tn_bf);
    convert_bf16_kernel<<<8192, 256, 0, stream>>>(w_net, wnet_bf);
    transpose_convert_kernel<<<dim3(16, 32), 256, 0, stream>>>(wq, wqt_bf, 1024, 512);
    transpose_convert_kernel<<<dim3(32, 32), 256, 0, stream>>>(wkv, wkvt_bf, 1024, 1024);
    transpose_convert_kernel<<<dim3(32, 16), 256, 0, stream>>>(wout, woutt_bf, 512, 1024);
    wgT_kernel<<<64, 256, 0, stream>>>(wg, wgT_bf);

    gates_kernel<<<128, 256, 0, stream>>>(tn_bf, wgT_bf, ws_g);

    // fused member linear + q projection (192 blocks)
    gemm_big<4><<<192, 512, 0, stream>>>(tok_bf, tn_bf, wnet_bf, wqt_bf, b_net,
                                         (void*)out_bf, (void*)q_bf);
    // kv = ctx @ wkv  (256 blocks)
    gemm_big<3><<<256, 512, 0, stream>>>(tok_bf, out_bf, wkvt_bf, nullptr, nullptr,
                                         (void*)kv_bf, nullptr);
    // attention + gating (merged heads)
    attn_kernel<<<BN_TOK, 512, 0, stream>>>(q_bf, kv_bf, ws_g, knw, og_bf);
    // pooled = og @ wout -> d_out (f32)
    gemm_big<0><<<128, 512, 0, stream>>>(og_bf, nullptr, woutt_bf, nullptr, nullptr,
                                         (void*)out, nullptr);
}

// Round 8
// 127.384 us; speedup vs baseline: 1.5779x; 1.1692x over previous
//
#include <hip/hip_runtime.h>
#include <hip/hip_bf16.h>
#include <math.h>

#define L_ 8
#define B_ 2
#define N_ 512
#define D_ 1024
#define H_ 8
#define DH_ 64
#define INNER_ 512
#define M_ 16
#define BN_TOK 1024            // B_*N_
#define EPS 1.1920928955078125e-07f
#define SCALE_ 0.125f          // DH^-0.5

typedef __attribute__((ext_vector_type(8))) __bf16 bf16x8;
typedef __attribute__((ext_vector_type(4))) __bf16 bf16x4;
typedef __attribute__((ext_vector_type(4))) float f32x4;

#define BARF() do { __builtin_amdgcn_s_barrier(); __builtin_amdgcn_sched_barrier(0); } while (0)
#define LGKM0() do { asm volatile("s_waitcnt lgkmcnt(0)" ::: "memory"); \
                     __builtin_amdgcn_sched_barrier(0); } while (0)
#define GLL(SRC, DST) __builtin_amdgcn_global_load_lds( \
    (const __attribute__((address_space(1))) void*)(SRC), \
    (__attribute__((address_space(3))) void*)(DST), 16, 0, 0)

// ---------------------------------------------------------------------------
// Consolidated prep: one dispatch.
//   blocks [0,8192):       rs + bf16 converts of tokens/tn (one row each)
//   blocks [8192,10240):   wnet f32->bf16 (4 float4 per thread)
//   blocks [10240,12288):  transposes wq/wkv/wout -> bf16 [N][K]
// ---------------------------------------------------------------------------
__device__ void transpose_body(const float* __restrict__ in,
                               __bf16* __restrict__ out, int R, int C,
                               int bx, int by)
{
    __shared__ float tile[32][33];
    const int x = threadIdx.x & 31, y = threadIdx.x >> 5;   // 32 x 8
    #pragma unroll
    for (int r = 0; r < 4; ++r)
        tile[y + r * 8][x] = in[(size_t)(by * 32 + y + r * 8) * C + bx * 32 + x];
    __syncthreads();
    #pragma unroll
    for (int r = 0; r < 4; ++r)
        out[(size_t)(bx * 32 + y + r * 8) * R + by * 32 + x] = (__bf16)tile[x][y + r * 8];
}

__global__ __launch_bounds__(256) void prep_kernel(
    const float* __restrict__ tokens, const float* __restrict__ norm_w,
    const float* __restrict__ w_net, const float* __restrict__ wq,
    const float* __restrict__ wkv, const float* __restrict__ wout,
    __bf16* __restrict__ tok_bf, __bf16* __restrict__ tn_bf,
    __bf16* __restrict__ wnet_bf, __bf16* __restrict__ wqt,
    __bf16* __restrict__ wkvt, __bf16* __restrict__ woutt)
{
    const int bid = blockIdx.x;
    const int t = threadIdx.x;

    if (bid < 8192) {
        // --- rs + bf16 convert, one (l,b,n) row ---
        const int wave = t >> 6, lane = t & 63;
        __shared__ float wsum[4];
        const float4 v = ((const float4*)(tokens + (size_t)bid * D_))[t];
        float ss = fmaf(v.x, v.x, fmaf(v.y, v.y, fmaf(v.z, v.z, v.w * v.w)));
        #pragma unroll
        for (int o = 1; o < 64; o <<= 1) ss += __shfl_xor(ss, o);
        if (lane == 0) wsum[wave] = ss;
        __syncthreads();
        const float rsv = rsqrtf((wsum[0] + wsum[1] + wsum[2] + wsum[3]) * (1.f / D_) + EPS);
        const float4 nw = ((const float4*)norm_w)[t];
        bf16x4 tb; tb.x = (__bf16)v.x; tb.y = (__bf16)v.y; tb.z = (__bf16)v.z; tb.w = (__bf16)v.w;
        ((bf16x4*)(tok_bf + (size_t)bid * D_))[t] = tb;
        bf16x4 nb;
        nb.x = (__bf16)(v.x * rsv * nw.x); nb.y = (__bf16)(v.y * rsv * nw.y);
        nb.z = (__bf16)(v.z * rsv * nw.z); nb.w = (__bf16)(v.w * rsv * nw.w);
        ((bf16x4*)(tn_bf + (size_t)bid * D_))[t] = nb;
    } else if (bid < 10240) {
        // --- wnet convert: 2048 blocks x 256 thr x 4 float4 ---
        const int base = (bid - 8192) * 1024 + t;
        #pragma unroll
        for (int j = 0; j < 4; ++j) {
            const int i = base + j * 256;
            float4 v = ((const float4*)w_net)[i];
            bf16x4 o;
            o.x = (__bf16)v.x; o.y = (__bf16)v.y; o.z = (__bf16)v.z; o.w = (__bf16)v.w;
            *(bf16x4*)(wnet_bf + (size_t)i * 4) = o;
        }
    } else {
        const int b2 = bid - 10240;
        if (b2 < 512)        transpose_body(wq, wqt, 1024, 512, b2 & 15, b2 >> 4);
        else if (b2 < 1536)  { const int b3 = b2 - 512;  transpose_body(wkv, wkvt, 1024, 1024, b3 & 31, b3 >> 5); }
        else                 { const int b3 = b2 - 1536; transpose_body(wout, woutt, 512, 1024, b3 & 31, b3 >> 5); }
    }
}

// ---------------------------------------------------------------------------
// Fused member linear + q projection + gates.
//   blocks [0,128):   member  out = tok @ wnet[l]^T + b   (256x256, CFG0)
//   blocks [128,192): q       q = tn @ wqt^T              (256x256, CFG0)
//   blocks [192,256): gates   sigmoid(tn @ wg)  (per-wave MFMA, reads wg f32)
// CFG0: BK=64, 8 waves (2m x 4n), wave tile 128x64, 4-phase schedule,
// T2 swizzle via pre-swizzled global source, counted vmcnt(4) per tile.
// ---------------------------------------------------------------------------
__global__ __launch_bounds__(512, 2) void gemm_fused(
    const __bf16* __restrict__ tok, const __bf16* __restrict__ tn,
    const __bf16* __restrict__ wnet, const __bf16* __restrict__ wqt,
    const float* __restrict__ bias, const float* __restrict__ wg,
    __bf16* __restrict__ out_bf, __bf16* __restrict__ q_bf,
    float* __restrict__ gates_out)
{
    __shared__ __align__(16) __bf16 As[2][256 * 64];   // 64 KiB
    __shared__ __align__(16) __bf16 Bs[2][256 * 64];   // 64 KiB

    constexpr int NT = 16, K = 1024;
    const int tid = threadIdx.x;
    const int w = tid >> 6, lane = tid & 63;
    const int fr = lane & 15, fq = lane >> 4;
    const int bid = blockIdx.x;

    if (bid >= 192) {
        // ---- gates path: 64 blocks x 8 waves, wave = 16 rows ----
        const int r0 = ((bid - 192) * 8 + w) * 16;
        const __bf16* arow = tn + (size_t)(r0 + fr) * D_ + fq * 8;
        f32x4 gacc = (f32x4){0.f, 0.f, 0.f, 0.f};
        for (int k0 = 0; k0 < D_; k0 += 32) {
            bf16x8 a = *(const bf16x8*)(arow + k0);
            bf16x8 b;
            #pragma unroll
            for (int j = 0; j < 8; ++j)
                b[j] = (fr < 8) ? (__bf16)wg[(size_t)(k0 + fq * 8 + j) * 8 + fr] : (__bf16)0.f;
            gacc = __builtin_amdgcn_mfma_f32_16x16x32_bf16(a, b, gacc, 0, 0, 0);
        }
        if (fr < 8) {
            #pragma unroll
            for (int r = 0; r < 4; ++r)
                gates_out[(size_t)(r0 + fq * 4 + r) * H_ + fr] = 1.f / (1.f + expf(-gacc[r]));
        }
        return;
    }

    // ---- member / q (CFG0) ----
    const int wm = w >> 2, wn = w & 3;
    const bool isq = bid >= 128;
    const int b2 = isq ? bid - 128 : bid;
    const int ntx = isq ? 2 : 4;
    const int c = b2 & 7, s = b2 >> 3;
    const int sq = s / ntx;
    const int m0 = (c * 4 + sq) * 256;
    const int n0 = (s - sq * ntx) * 256;
    const __bf16* Ab;
    const __bf16* Btb;
    const float* biasp = nullptr;
    int Ncols;
    if (isq) {
        Ab = tn + (size_t)m0 * K; Btb = wqt + (size_t)n0 * K; Ncols = 512;
    } else {
        Ab = tok + (size_t)m0 * K;
        Btb = wnet + (size_t)(m0 >> 10) * 1024 * K + (size_t)n0 * K;
        Ncols = 1024;
        biasp = bias + (size_t)(m0 >> 10) * 1024;
    }

    const int lrow = lane >> 3;
    const int lchunk = (lane & 7) ^ lrow;
    const int fo0 = ((fq ^ (lane & 7)) << 4);
    const int fo1 = (((4 + fq) ^ (lane & 7)) << 4);

#define STAGE_A(T2, PB, HALF) do {                                            \
    _Pragma("unroll")                                                         \
    for (int ld = (HALF) * 2; ld < (HALF) * 2 + 2; ++ld)                      \
        GLL(Ab + (size_t)(w * 32 + ld * 8 + lrow) * K + (T2) * 64 + lchunk * 8, \
            &As[PB][(w * 32 + ld * 8) * 64]);                                 \
} while (0)
#define STAGE_B(T2, PB, HALF) do {                                            \
    _Pragma("unroll")                                                         \
    for (int ld = (HALF) * 2; ld < (HALF) * 2 + 2; ++ld)                      \
        GLL(Btb + (size_t)(w * 32 + ld * 8 + lrow) * K + (T2) * 64 + lchunk * 8, \
            &Bs[PB][(w * 32 + ld * 8) * 64]);                                 \
} while (0)
#define RD_A(DST, MIOFF, FO) do {                                             \
    _Pragma("unroll")                                                         \
    for (int mi = 0; mi < 4; ++mi)                                            \
        (DST)[mi] = *(const bf16x8*)(Ap + ((wm * 128 + ((MIOFF) + mi) * 16 + fr) << 7) + (FO)); \
} while (0)
#define RD_B(DST, FO) do {                                                    \
    _Pragma("unroll")                                                         \
    for (int nj = 0; nj < 4; ++nj)                                            \
        (DST)[nj] = *(const bf16x8*)(Bp + ((wn * 64 + nj * 16 + fr) << 7) + (FO)); \
} while (0)
#define MFMA16(AFR, BFR, AOFF) do {                                           \
    _Pragma("unroll")                                                         \
    for (int mi = 0; mi < 4; ++mi)                                            \
        _Pragma("unroll")                                                     \
        for (int nj = 0; nj < 4; ++nj)                                        \
            acc[(AOFF) + mi][nj] = __builtin_amdgcn_mfma_f32_16x16x32_bf16(   \
                (AFR)[mi], (BFR)[nj], acc[(AOFF) + mi][nj], 0, 0, 0);         \
} while (0)

    f32x4 acc[8][4];
    #pragma unroll
    for (int mi = 0; mi < 8; ++mi)
        #pragma unroll
        for (int nj = 0; nj < 4; ++nj)
            acc[mi][nj] = (f32x4){0.f, 0.f, 0.f, 0.f};

    STAGE_A(0, 0, 0); STAGE_A(0, 0, 1);
    STAGE_B(0, 0, 0); STAGE_B(0, 0, 1);
    STAGE_A(1, 1, 0); STAGE_A(1, 1, 1);
    asm volatile("s_waitcnt vmcnt(4)" ::: "memory");
    BARF();

    for (int t = 0; t < NT; ++t) {
        const int p = t & 1;
        const char* Ap = (const char*)&As[p][0];
        const char* Bp = (const char*)&Bs[p][0];
        bf16x8 am0k0[4], am1k0[4], bk0[4], am0k1[4], am1k1[4], bk1[4];

        // ph0: k0 frags (compiler-tracked waits); stage B(t+1)h0
        RD_A(am0k0, 0, fo0); RD_B(bk0, fo0); RD_A(am1k0, 4, fo0);
        if (t + 1 < NT) STAGE_B(t + 1, p ^ 1, 0);
        BARF();
        __builtin_amdgcn_s_setprio(1);
        MFMA16(am0k0, bk0, 0);
        __builtin_amdgcn_s_setprio(0);
        BARF();

        // ph1: k1 frags; stage B(t+1)h1; MFMA m1k0
        RD_A(am0k1, 0, fo1); RD_B(bk1, fo1); RD_A(am1k1, 4, fo1);
        if (t + 1 < NT) STAGE_B(t + 1, p ^ 1, 1);
        BARF();
        __builtin_amdgcn_s_setprio(1);
        MFMA16(am1k0, bk0, 4);
        __builtin_amdgcn_s_setprio(0);
        LGKM0();                       // all As[p]/Bs[p] reads complete
        BARF();

        // ph2: stage A(t+2)h0 into As[p]; MFMA m0k1
        if (t + 2 < NT) STAGE_A(t + 2, p, 0);
        __builtin_amdgcn_s_setprio(1);
        MFMA16(am0k1, bk1, 0);
        __builtin_amdgcn_s_setprio(0);
        BARF();

        // ph3: stage A(t+2)h1; MFMA m1k1; counted vmcnt; tile-end barrier
        if (t + 2 < NT) STAGE_A(t + 2, p, 1);
        __builtin_amdgcn_s_setprio(1);
        MFMA16(am1k1, bk1, 4);
        __builtin_amdgcn_s_setprio(0);
        if (t + 2 < NT) { asm volatile("s_waitcnt vmcnt(4)" ::: "memory"); }
        else            { asm volatile("s_waitcnt vmcnt(0)" ::: "memory"); }
        BARF();
    }

    #pragma unroll
    for (int mi = 0; mi < 8; ++mi) {
        const int r0 = m0 + wm * 128 + mi * 16 + fq * 4;
        #pragma unroll
        for (int nj = 0; nj < 4; ++nj) {
            const int col = n0 + wn * 64 + nj * 16 + fr;
            const float badd = (biasp != nullptr) ? biasp[col] : 0.f;
            __bf16* Co = isq ? q_bf : out_bf;
            #pragma unroll
            for (int r = 0; r < 4; ++r)
                Co[(size_t)(r0 + r) * Ncols + col] = (__bf16)(acc[mi][nj][r] + badd);
        }
    }
#undef STAGE_A
#undef STAGE_B
#undef RD_A
#undef RD_B
#undef MFMA16
}

// ---------------------------------------------------------------------------
// kv GEMM (CFG0, row-gather at 8192): kv = [tok; out] @ wkvt^T, 256 blocks.
// ---------------------------------------------------------------------------
__global__ __launch_bounds__(512, 2) void gemm_kv(
    const __bf16* __restrict__ tok, const __bf16* __restrict__ outm,
    const __bf16* __restrict__ wkvt, __bf16* __restrict__ kv_bf)
{
    __shared__ __align__(16) __bf16 As[2][256 * 64];
    __shared__ __align__(16) __bf16 Bs[2][256 * 64];
    constexpr int NT = 16, K = 1024, Ncols = 1024;
    const int tid = threadIdx.x;
    const int w = tid >> 6, lane = tid & 63;
    const int wm = w >> 2, wn = w & 3;
    const int fr = lane & 15, fq = lane >> 4;
    const int bid = blockIdx.x;
    const int c = bid & 7, s = bid >> 3;
    const int sq = s >> 2;                 // ntx = 4
    const int m0 = (c * 8 + sq) * 256;     // nty/8 = 8
    const int n0 = (s - sq * 4) * 256;
    const __bf16* Ab = (m0 >= 8192) ? (outm + (size_t)(m0 - 8192) * K)
                                    : (tok + (size_t)m0 * K);
    const __bf16* Btb = wkvt + (size_t)n0 * K;

    const int lrow = lane >> 3;
    const int lchunk = (lane & 7) ^ lrow;
    const int fo0 = ((fq ^ (lane & 7)) << 4);
    const int fo1 = (((4 + fq) ^ (lane & 7)) << 4);

#define STAGE_A(T2, PB, HALF) do {                                            \
    _Pragma("unroll")                                                         \
    for (int ld = (HALF) * 2; ld < (HALF) * 2 + 2; ++ld)                      \
        GLL(Ab + (size_t)(w * 32 + ld * 8 + lrow) * K + (T2) * 64 + lchunk * 8, \
            &As[PB][(w * 32 + ld * 8) * 64]);                                 \
} while (0)
#define STAGE_B(T2, PB, HALF) do {                                            \
    _Pragma("unroll")                                                         \
    for (int ld = (HALF) * 2; ld < (HALF) * 2 + 2; ++ld)                      \
        GLL(Btb + (size_t)(w * 32 + ld * 8 + lrow) * K + (T2) * 64 + lchunk * 8, \
            &Bs[PB][(w * 32 + ld * 8) * 64]);                                 \
} while (0)
#define RD_A(DST, MIOFF, FO) do {                                             \
    _Pragma("unroll")                                                         \
    for (int mi = 0; mi < 4; ++mi)                                            \
        (DST)[mi] = *(const bf16x8*)(Ap + ((wm * 128 + ((MIOFF) + mi) * 16 + fr) << 7) + (FO)); \
} while (0)
#define RD_B(DST, FO) do {                                                    \
    _Pragma("unroll")                                                         \
    for (int nj = 0; nj < 4; ++nj)                                            \
        (DST)[nj] = *(const bf16x8*)(Bp + ((wn * 64 + nj * 16 + fr) << 7) + (FO)); \
} while (0)
#define MFMA16(AFR, BFR, AOFF) do {                                           \
    _Pragma("unroll")                                                         \
    for (int mi = 0; mi < 4; ++mi)                                            \
        _Pragma("unroll")                                                     \
        for (int nj = 0; nj < 4; ++nj)                                        \
            acc[(AOFF) + mi][nj] = __builtin_amdgcn_mfma_f32_16x16x32_bf16(   \
                (AFR)[mi], (BFR)[nj], acc[(AOFF) + mi][nj], 0, 0, 0);         \
} while (0)

    f32x4 acc[8][4];
    #pragma unroll
    for (int mi = 0; mi < 8; ++mi)
        #pragma unroll
        for (int nj = 0; nj < 4; ++nj)
            acc[mi][nj] = (f32x4){0.f, 0.f, 0.f, 0.f};

    STAGE_A(0, 0, 0); STAGE_A(0, 0, 1);
    STAGE_B(0, 0, 0); STAGE_B(0, 0, 1);
    STAGE_A(1, 1, 0); STAGE_A(1, 1, 1);
    asm volatile("s_waitcnt vmcnt(4)" ::: "memory");
    BARF();

    for (int t = 0; t < NT; ++t) {
        const int p = t & 1;
        const char* Ap = (const char*)&As[p][0];
        const char* Bp = (const char*)&Bs[p][0];
        bf16x8 am0k0[4], am1k0[4], bk0[4], am0k1[4], am1k1[4], bk1[4];

        RD_A(am0k0, 0, fo0); RD_B(bk0, fo0); RD_A(am1k0, 4, fo0);
        if (t + 1 < NT) STAGE_B(t + 1, p ^ 1, 0);
        BARF();
        __builtin_amdgcn_s_setprio(1);
        MFMA16(am0k0, bk0, 0);
        __builtin_amdgcn_s_setprio(0);
        BARF();

        RD_A(am0k1, 0, fo1); RD_B(bk1, fo1); RD_A(am1k1, 4, fo1);
        if (t + 1 < NT) STAGE_B(t + 1, p ^ 1, 1);
        BARF();
        __builtin_amdgcn_s_setprio(1);
        MFMA16(am1k0, bk0, 4);
        __builtin_amdgcn_s_setprio(0);
        LGKM0();
        BARF();

        if (t + 2 < NT) STAGE_A(t + 2, p, 0);
        __builtin_amdgcn_s_setprio(1);
        MFMA16(am0k1, bk1, 0);
        __builtin_amdgcn_s_setprio(0);
        BARF();

        if (t + 2 < NT) STAGE_A(t + 2, p, 1);
        __builtin_amdgcn_s_setprio(1);
        MFMA16(am1k1, bk1, 4);
        __builtin_amdgcn_s_setprio(0);
        if (t + 2 < NT) { asm volatile("s_waitcnt vmcnt(4)" ::: "memory"); }
        else            { asm volatile("s_waitcnt vmcnt(0)" ::: "memory"); }
        BARF();
    }

    #pragma unroll
    for (int mi = 0; mi < 8; ++mi) {
        const int r0 = m0 + wm * 128 + mi * 16 + fq * 4;
        #pragma unroll
        for (int nj = 0; nj < 4; ++nj) {
            const int col = n0 + wn * 64 + nj * 16 + fr;
            #pragma unroll
            for (int r = 0; r < 4; ++r)
                kv_bf[(size_t)(r0 + r) * Ncols + col] = (__bf16)acc[mi][nj][r];
        }
    }
#undef STAGE_A
#undef STAGE_B
#undef RD_A
#undef RD_B
#undef MFMA16
}

// ---------------------------------------------------------------------------
// final GEMM, CFG1: BM=256 BN=128, 8 waves (4m x 2n), wave tile 64x64,
// acc[4][4].  M=8192, N=1024, K=512 -> 32x8 = 256 blocks (full machine).
// LDS: A 2x32KB + B 2x16KB = 96 KB.  Same k-order as before (bit-identical).
// ---------------------------------------------------------------------------
__global__ __launch_bounds__(512, 2) void gemm_final(
    const __bf16* __restrict__ A,      // og [8192][512]
    const __bf16* __restrict__ Bt,     // woutt [1024][512]
    float* __restrict__ Cf)            // out [8192][1024] f32
{
    __shared__ __align__(16) __bf16 As[2][256 * 64];   // 64 KiB
    __shared__ __align__(16) __bf16 Bs[2][128 * 64];   // 32 KiB
    constexpr int NT = 8, K = 512, Ncols = 1024;
    const int tid = threadIdx.x;
    const int w = tid >> 6, lane = tid & 63;
    const int wm = w >> 1, wn = w & 1;
    const int fr = lane & 15, fq = lane >> 4;
    const int bid = blockIdx.x;
    const int c = bid & 7, s = bid >> 3;
    const int sq = s >> 3;                 // ntx = 8
    const int m0 = (c * 4 + sq) * 256;     // nty/8 = 4
    const int n0 = (s - sq * 8) * 128;
    const __bf16* Ab = A + (size_t)m0 * K;
    const __bf16* Btb = Bt + (size_t)n0 * K;

    const int lrow = lane >> 3;
    const int lchunk = (lane & 7) ^ lrow;
    const int fo0 = ((fq ^ (lane & 7)) << 4);
    const int fo1 = (((4 + fq) ^ (lane & 7)) << 4);

#define STAGE_A(T2, PB, HALF) do {                                            \
    _Pragma("unroll")                                                         \
    for (int ld = (HALF) * 2; ld < (HALF) * 2 + 2; ++ld)                      \
        GLL(Ab + (size_t)(w * 32 + ld * 8 + lrow) * K + (T2) * 64 + lchunk * 8, \
            &As[PB][(w * 32 + ld * 8) * 64]);                                 \
} while (0)
#define STAGE_B(T2, PB, HALF)                                                 \
    GLL(Btb + (size_t)(w * 16 + (HALF) * 8 + lrow) * K + (T2) * 64 + lchunk * 8, \
        &Bs[PB][(w * 16 + (HALF) * 8) * 64])
#define RD_A(DST, FO) do {                                                    \
    _Pragma("unroll")                                                         \
    for (int mi = 0; mi < 4; ++mi)                                            \
        (DST)[mi] = *(const bf16x8*)(Ap + ((wm * 64 + mi * 16 + fr) << 7) + (FO)); \
} while (0)
#define RD_B(DST, FO) do {                                                    \
    _Pragma("unroll")                                                         \
    for (int nj = 0; nj < 4; ++nj)                                            \
        (DST)[nj] = *(const bf16x8*)(Bp + ((wn * 64 + nj * 16 + fr) << 7) + (FO)); \
} while (0)
#define MFMA16C1(AFR, BFR) do {                                               \
    _Pragma("unroll")                                                         \
    for (int mi = 0; mi < 4; ++mi)                                            \
        _Pragma("unroll")                                                     \
        for (int nj = 0; nj < 4; ++nj)                                        \
            acc[mi][nj] = __builtin_amdgcn_mfma_f32_16x16x32_bf16(            \
                (AFR)[mi], (BFR)[nj], acc[mi][nj], 0, 0, 0);                  \
} while (0)

    f32x4 acc[4][4];
    #pragma unroll
    for (int mi = 0; mi < 4; ++mi)
        #pragma unroll
        for (int nj = 0; nj < 4; ++nj)
            acc[mi][nj] = (f32x4){0.f, 0.f, 0.f, 0.f};

    // prologue: A0(4 GLL) + B0(2) + A1(4) = 10; vmcnt(4) -> A0,B0 landed.
    STAGE_A(0, 0, 0); STAGE_A(0, 0, 1);
    STAGE_B(0, 0, 0); STAGE_B(0, 0, 1);
    STAGE_A(1, 1, 0); STAGE_A(1, 1, 1);
    asm volatile("s_waitcnt vmcnt(4)" ::: "memory");
    BARF();

    for (int t = 0; t < NT; ++t) {
        const int p = t & 1;
        const char* Ap = (const char*)&As[p][0];
        const char* Bp = (const char*)&Bs[p][0];
        bf16x8 ak0[4], bk0[4], ak1[4], bk1[4];

        // ph0: k0 frags; stage B(t+1)h0 (1 GLL)
        RD_A(ak0, fo0); RD_B(bk0, fo0);
        if (t + 1 < NT) STAGE_B(t + 1, p ^ 1, 0);
        BARF();
        __builtin_amdgcn_s_setprio(1);
        MFMA16C1(ak0, bk0);
        __builtin_amdgcn_s_setprio(0);
        BARF();

        // ph1: k1 frags; stage B(t+1)h1; MFMA k1; full LDS drain
        RD_A(ak1, fo1); RD_B(bk1, fo1);
        if (t + 1 < NT) STAGE_B(t + 1, p ^ 1, 1);
        BARF();
        __builtin_amdgcn_s_setprio(1);
        MFMA16C1(ak1, bk1);
        __builtin_amdgcn_s_setprio(0);
        LGKM0();
        BARF();

        // ph2: stage A(t+2) both halves; counted vmcnt
        if (t + 2 < NT) { STAGE_A(t + 2, p, 0); STAGE_A(t + 2, p, 1); }
        if (t + 2 < NT) { asm volatile("s_waitcnt vmcnt(4)" ::: "memory"); }
        else            { asm volatile("s_waitcnt vmcnt(0)" ::: "memory"); }
        BARF();
    }

    #pragma unroll
    for (int mi = 0; mi < 4; ++mi) {
        const int r0 = m0 + wm * 64 + mi * 16 + fq * 4;
        #pragma unroll
        for (int nj = 0; nj < 4; ++nj) {
            const int col = n0 + wn * 64 + nj * 16 + fr;
            #pragma unroll
            for (int r = 0; r < 4; ++r)
                Cf[(size_t)(r0 + r) * Ncols + col] = acc[mi][nj][r];
        }
    }
#undef STAGE_A
#undef STAGE_B
#undef RD_A
#undef RD_B
#undef MFMA16C1
}

// ---------------------------------------------------------------------------
// Merged-heads attention: one 512-thread block per (b,n) site; wave = head.
// ---------------------------------------------------------------------------
__global__ __launch_bounds__(512) void attn_kernel(
    const __bf16* __restrict__ q,     // [8192, 512]
    const __bf16* __restrict__ kv,    // [16384, 1024]  (k | v)
    const float* __restrict__ gates,  // [8192, 8]
    const float* __restrict__ knw,    // [64]
    __bf16* __restrict__ og)          // [8192, 512]
{
    const int bn = blockIdx.x;        // 0..1023
    const int tid = threadIdx.x;
    const int h = tid >> 6, lane = tid & 63;

    __shared__ __align__(16) __bf16 qs[8][520];
    __shared__ __align__(16) __bf16 kvs[16][1032];
    __shared__ float ssm[8][8][17];   // [h][l][m]
    __shared__ float kn[64];
    __shared__ float gs[64];          // [l*8+h]

    {
        const int l = tid >> 6, c8 = tid & 63;
        *(bf16x8*)&qs[l][c8 * 8] =
            *(const bf16x8*)(q + ((size_t)(l * BN_TOK + bn)) * INNER_ + c8 * 8);
    }
    #pragma unroll
    for (int i = 0; i < 4; ++i) {
        const int g = tid + i * 512;
        const int m = g >> 7, c8 = g & 127;
        *(bf16x8*)&kvs[m][c8 * 8] =
            *(const bf16x8*)(kv + ((size_t)(m * BN_TOK + bn)) * 1024 + c8 * 8);
    }
    if (tid < 64) {
        kn[tid] = knw[tid];
        gs[tid] = gates[((size_t)((tid >> 3) * BN_TOK + bn)) * H_ + (tid & 7)];
    }
    __syncthreads();

    const int m = lane & 15, grp = lane >> 4;

    float s2 = 0.f;
    #pragma unroll
    for (int j = 0; j < 16; ++j) {
        float v = (float)kvs[m][h * DH_ + grp * 16 + j];
        s2 = fmaf(v, v, s2);
    }
    s2 += __shfl_xor(s2, 16);
    s2 += __shfl_xor(s2, 32);
    const float kscale = rsqrtf(s2 * (1.f / DH_) + EPS) * SCALE_;

    const int l0 = grp, l1 = grp + 4;
    float sim0 = 0.f, sim1 = 0.f;
    #pragma unroll
    for (int d = 0; d < DH_; ++d) {
        const float kf = (float)kvs[m][h * DH_ + d] * kn[d];
        sim0 = fmaf((float)qs[l0][h * DH_ + d], kf, sim0);
        sim1 = fmaf((float)qs[l1][h * DH_ + d], kf, sim1);
    }
    sim0 *= kscale; sim1 *= kscale;

    float mx0 = sim0, mx1 = sim1;
    #pragma unroll
    for (int o = 1; o < 16; o <<= 1) {
        mx0 = fmaxf(mx0, __shfl_xor(mx0, o));
        mx1 = fmaxf(mx1, __shfl_xor(mx1, o));
    }
    float e0 = expf(sim0 - mx0), e1 = expf(sim1 - mx1);
    float sm0 = e0, sm1 = e1;
    #pragma unroll
    for (int o = 1; o < 16; o <<= 1) {
        sm0 += __shfl_xor(sm0, o);
        sm1 += __shfl_xor(sm1, o);
    }
    ssm[h][l0][m] = e0 / sm0;
    ssm[h][l1][m] = e1 / sm1;

    float vf[16];
    #pragma unroll
    for (int mm = 0; mm < 16; ++mm)
        vf[mm] = (float)kvs[mm][INNER_ + h * DH_ + lane];
    #pragma unroll
    for (int l = 0; l < 8; ++l) {
        float o = 0.f;
        #pragma unroll
        for (int mm = 0; mm < 16; ++mm) o = fmaf(ssm[h][l][mm], vf[mm], o);
        og[((size_t)(l * BN_TOK + bn)) * INNER_ + h * DH_ + lane] =
            (__bf16)(o * gs[l * 8 + h]);
    }
}

// ---------------------------------------------------------------------------
extern "C" void kernel_launch(void* const* d_in, const int* in_sizes, int n_in,
                              void* d_out, int out_size, void* d_ws, size_t ws_size,
                              hipStream_t stream)
{
    const float* tokens = (const float*)d_in[0];  // [8,2,512,1024]
    const float* w_net  = (const float*)d_in[1];  // [8,1024,1024]
    const float* b_net  = (const float*)d_in[2];  // [8,1024]
    const float* norm_w = (const float*)d_in[3];  // [1024]
    const float* wq     = (const float*)d_in[4];  // [1024,512]
    const float* wkv    = (const float*)d_in[5];  // [1024,1024]
    const float* knw    = (const float*)d_in[6];  // [64]
    const float* wg     = (const float*)d_in[7];  // [1024,8]
    const float* wout   = (const float*)d_in[8];  // [512,1024]
    float* out = (float*)d_out;                   // [8,2,512,1024]

    char* ws = (char*)d_ws;
    __bf16* tok_bf  = (__bf16*)(ws);                         // 16,777,216 B
    __bf16* tn_bf   = (__bf16*)(ws + 16777216);              // 16,777,216
    __bf16* out_bf  = (__bf16*)(ws + 33554432);              // 16,777,216
    __bf16* q_bf    = (__bf16*)(ws + 50331648);              //  8,388,608
    __bf16* kv_bf   = (__bf16*)(ws + 58720256);              // 33,554,432
    __bf16* og_bf   = (__bf16*)(ws + 92274688);              //  8,388,608
    __bf16* wnet_bf = (__bf16*)(ws + 100663296);             // 16,777,216
    __bf16* wqt_bf  = (__bf16*)(ws + 117440512);             //  1,048,576
    __bf16* wkvt_bf = (__bf16*)(ws + 118489088);             //  2,097,152
    __bf16* woutt_bf= (__bf16*)(ws + 120586240);             //  1,048,576
    float*  ws_g    = (float*)(ws + 121667584);              //    262,144

    // 1. consolidated prep (rs + all weight conversions)
    prep_kernel<<<12288, 256, 0, stream>>>(tokens, norm_w, w_net, wq, wkv, wout,
                                           tok_bf, tn_bf, wnet_bf, wqt_bf,
                                           wkvt_bf, woutt_bf);
    // 2. member + q + gates (256 blocks, full machine)
    gemm_fused<<<256, 512, 0, stream>>>(tok_bf, tn_bf, wnet_bf, wqt_bf, b_net,
                                        wg, out_bf, q_bf, ws_g);
    // 3. kv = [tok; out] @ wkv (256 blocks)
    gemm_kv<<<256, 512, 0, stream>>>(tok_bf, out_bf, wkvt_bf, kv_bf);
    // 4. attention + gating
    attn_kernel<<<BN_TOK, 512, 0, stream>>>(q_bf, kv_bf, ws_g, knw, og_bf);
    // 5. pooled = og @ wout -> d_out (f32, 256 blocks CFG1)
    gemm_final<<<256, 512, 0, stream>>>(og_bf, woutt_bf, out);
}

// Round 9
// 126.163 us; speedup vs baseline: 1.5931x; 1.0097x over previous
//
#include <hip/hip_runtime.h>
#include <hip/hip_bf16.h>
#include <math.h>

#define L_ 8
#define B_ 2
#define N_ 512
#define D_ 1024
#define H_ 8
#define DH_ 64
#define INNER_ 512
#define M_ 16
#define BN_TOK 1024            // B_*N_
#define EPS 1.1920928955078125e-07f
#define SCALE_ 0.125f          // DH^-0.5

typedef __attribute__((ext_vector_type(8))) __bf16 bf16x8;
typedef __attribute__((ext_vector_type(4))) __bf16 bf16x4;
typedef __attribute__((ext_vector_type(4))) float f32x4;

#define BARF() do { __builtin_amdgcn_s_barrier(); __builtin_amdgcn_sched_barrier(0); } while (0)
#define LGKM0() do { asm volatile("s_waitcnt lgkmcnt(0)" ::: "memory"); \
                     __builtin_amdgcn_sched_barrier(0); } while (0)
#define GLL(SRC, DST) __builtin_amdgcn_global_load_lds( \
    (const __attribute__((address_space(1))) void*)(SRC), \
    (__attribute__((address_space(3))) void*)(DST), 16, 0, 0)

// ---------------------------------------------------------------------------
// Consolidated prep: one dispatch.
//   [0,8192):      rs + bf16 converts of tokens/tn (one row each)
//   [8192,10240):  wnet f32->bf16
//   [10240,12288): transposes wq/wkv/wout -> bf16 [N][K]
//   [12288,12352): wgT build (wg [1024][8] f32 -> [16][1024] bf16, rows 8+ =0)
// ---------------------------------------------------------------------------
__device__ void transpose_body(const float* __restrict__ in,
                               __bf16* __restrict__ out, int R, int C,
                               int bx, int by)
{
    __shared__ float tile[32][33];
    const int x = threadIdx.x & 31, y = threadIdx.x >> 5;   // 32 x 8
    #pragma unroll
    for (int r = 0; r < 4; ++r)
        tile[y + r * 8][x] = in[(size_t)(by * 32 + y + r * 8) * C + bx * 32 + x];
    __syncthreads();
    #pragma unroll
    for (int r = 0; r < 4; ++r)
        out[(size_t)(bx * 32 + y + r * 8) * R + by * 32 + x] = (__bf16)tile[x][y + r * 8];
}

__global__ __launch_bounds__(256) void prep_kernel(
    const float* __restrict__ tokens, const float* __restrict__ norm_w,
    const float* __restrict__ w_net, const float* __restrict__ wq,
    const float* __restrict__ wkv, const float* __restrict__ wout,
    const float* __restrict__ wg,
    __bf16* __restrict__ tok_bf, __bf16* __restrict__ tn_bf,
    __bf16* __restrict__ wnet_bf, __bf16* __restrict__ wqt,
    __bf16* __restrict__ wkvt, __bf16* __restrict__ woutt,
    __bf16* __restrict__ wgT)
{
    const int bid = blockIdx.x;
    const int t = threadIdx.x;

    if (bid < 8192) {
        // --- rs + bf16 convert, one (l,b,n) row ---
        const int wave = t >> 6, lane = t & 63;
        __shared__ float wsum[4];
        const float4 v = ((const float4*)(tokens + (size_t)bid * D_))[t];
        float ss = fmaf(v.x, v.x, fmaf(v.y, v.y, fmaf(v.z, v.z, v.w * v.w)));
        #pragma unroll
        for (int o = 1; o < 64; o <<= 1) ss += __shfl_xor(ss, o);
        if (lane == 0) wsum[wave] = ss;
        __syncthreads();
        const float rsv = rsqrtf((wsum[0] + wsum[1] + wsum[2] + wsum[3]) * (1.f / D_) + EPS);
        const float4 nw = ((const float4*)norm_w)[t];
        bf16x4 tb; tb.x = (__bf16)v.x; tb.y = (__bf16)v.y; tb.z = (__bf16)v.z; tb.w = (__bf16)v.w;
        ((bf16x4*)(tok_bf + (size_t)bid * D_))[t] = tb;
        bf16x4 nb;
        nb.x = (__bf16)(v.x * rsv * nw.x); nb.y = (__bf16)(v.y * rsv * nw.y);
        nb.z = (__bf16)(v.z * rsv * nw.z); nb.w = (__bf16)(v.w * rsv * nw.w);
        ((bf16x4*)(tn_bf + (size_t)bid * D_))[t] = nb;
    } else if (bid < 10240) {
        // --- wnet convert ---
        const int base = (bid - 8192) * 1024 + t;
        #pragma unroll
        for (int j = 0; j < 4; ++j) {
            const int i = base + j * 256;
            float4 v = ((const float4*)w_net)[i];
            bf16x4 o;
            o.x = (__bf16)v.x; o.y = (__bf16)v.y; o.z = (__bf16)v.z; o.w = (__bf16)v.w;
            *(bf16x4*)(wnet_bf + (size_t)i * 4) = o;
        }
    } else if (bid < 12288) {
        const int b2 = bid - 10240;
        if (b2 < 512)        transpose_body(wq, wqt, 1024, 512, b2 & 15, b2 >> 4);
        else if (b2 < 1536)  { const int b3 = b2 - 512;  transpose_body(wkv, wkvt, 1024, 1024, b3 & 31, b3 >> 5); }
        else                 { const int b3 = b2 - 1536; transpose_body(wout, woutt, 512, 1024, b3 & 31, b3 >> 5); }
    } else {
        // --- wgT build: 64 blocks x 256 thr = 16384 elems ---
        const int g = (bid - 12288) * 256 + t;
        const int h = g >> 10, d = g & 1023;
        wgT[g] = (h < 8) ? (__bf16)wg[d * 8 + h] : (__bf16)0.f;
    }
}

// ---------------------------------------------------------------------------
// Fused member linear + q projection + gates.
//   [0,128):   member  out = tok @ wnet[l]^T + b   (256x256, CFG0)
//   [128,192): q       q = tn @ wqt^T              (256x256, CFG0)
//   [192,256): gates   sigmoid(tn @ wgT^T)  (per-wave MFMA, bf16x8, unroll 8)
// ---------------------------------------------------------------------------
__global__ __launch_bounds__(512, 2) void gemm_fused(
    const __bf16* __restrict__ tok, const __bf16* __restrict__ tn,
    const __bf16* __restrict__ wnet, const __bf16* __restrict__ wqt,
    const float* __restrict__ bias, const __bf16* __restrict__ wgT,
    __bf16* __restrict__ out_bf, __bf16* __restrict__ q_bf,
    float* __restrict__ gates_out)
{
    __shared__ __align__(16) __bf16 As[2][256 * 64];   // 64 KiB
    __shared__ __align__(16) __bf16 Bs[2][256 * 64];   // 64 KiB

    constexpr int NT = 16, K = 1024;
    const int tid = threadIdx.x;
    const int w = tid >> 6, lane = tid & 63;
    const int fr = lane & 15, fq = lane >> 4;
    const int bid = blockIdx.x;

    if (bid >= 192) {
        // ---- gates path (R7-verified body): wave = 16 rows ----
        const int r0 = ((bid - 192) * 8 + w) * 16;
        const __bf16* arow = tn + (size_t)(r0 + fr) * D_ + fq * 8;
        const __bf16* brow = wgT + (size_t)fr * D_ + fq * 8;
        f32x4 gacc = (f32x4){0.f, 0.f, 0.f, 0.f};
        #pragma unroll 8
        for (int k0 = 0; k0 < D_; k0 += 32) {
            bf16x8 a = *(const bf16x8*)(arow + k0);
            bf16x8 b = *(const bf16x8*)(brow + k0);
            gacc = __builtin_amdgcn_mfma_f32_16x16x32_bf16(a, b, gacc, 0, 0, 0);
        }
        if (fr < 8) {
            #pragma unroll
            for (int r = 0; r < 4; ++r)
                gates_out[(size_t)(r0 + fq * 4 + r) * H_ + fr] = 1.f / (1.f + expf(-gacc[r]));
        }
        return;
    }

    // ---- member / q (CFG0) ----
    const int wm = w >> 2, wn = w & 3;
    const bool isq = bid >= 128;
    const int b2 = isq ? bid - 128 : bid;
    const int ntx = isq ? 2 : 4;
    const int c = b2 & 7, s = b2 >> 3;
    const int sq = s / ntx;
    const int m0 = (c * 4 + sq) * 256;
    const int n0 = (s - sq * ntx) * 256;
    const __bf16* Ab;
    const __bf16* Btb;
    const float* biasp = nullptr;
    int Ncols;
    if (isq) {
        Ab = tn + (size_t)m0 * K; Btb = wqt + (size_t)n0 * K; Ncols = 512;
    } else {
        Ab = tok + (size_t)m0 * K;
        Btb = wnet + (size_t)(m0 >> 10) * 1024 * K + (size_t)n0 * K;
        Ncols = 1024;
        biasp = bias + (size_t)(m0 >> 10) * 1024;
    }

    const int lrow = lane >> 3;
    const int lchunk = (lane & 7) ^ lrow;
    const int fo0 = ((fq ^ (lane & 7)) << 4);
    const int fo1 = (((4 + fq) ^ (lane & 7)) << 4);

#define STAGE_A(T2, PB, HALF) do {                                            \
    _Pragma("unroll")                                                         \
    for (int ld = (HALF) * 2; ld < (HALF) * 2 + 2; ++ld)                      \
        GLL(Ab + (size_t)(w * 32 + ld * 8 + lrow) * K + (T2) * 64 + lchunk * 8, \
            &As[PB][(w * 32 + ld * 8) * 64]);                                 \
} while (0)
#define STAGE_B(T2, PB, HALF) do {                                            \
    _Pragma("unroll")                                                         \
    for (int ld = (HALF) * 2; ld < (HALF) * 2 + 2; ++ld)                      \
        GLL(Btb + (size_t)(w * 32 + ld * 8 + lrow) * K + (T2) * 64 + lchunk * 8, \
            &Bs[PB][(w * 32 + ld * 8) * 64]);                                 \
} while (0)
#define RD_A(DST, MIOFF, FO) do {                                             \
    _Pragma("unroll")                                                         \
    for (int mi = 0; mi < 4; ++mi)                                            \
        (DST)[mi] = *(const bf16x8*)(Ap + ((wm * 128 + ((MIOFF) + mi) * 16 + fr) << 7) + (FO)); \
} while (0)
#define RD_B(DST, FO) do {                                                    \
    _Pragma("unroll")                                                         \
    for (int nj = 0; nj < 4; ++nj)                                            \
        (DST)[nj] = *(const bf16x8*)(Bp + ((wn * 64 + nj * 16 + fr) << 7) + (FO)); \
} while (0)
#define MFMA16(AFR, BFR, AOFF) do {                                           \
    _Pragma("unroll")                                                         \
    for (int mi = 0; mi < 4; ++mi)                                            \
        _Pragma("unroll")                                                     \
        for (int nj = 0; nj < 4; ++nj)                                        \
            acc[(AOFF) + mi][nj] = __builtin_amdgcn_mfma_f32_16x16x32_bf16(   \
                (AFR)[mi], (BFR)[nj], acc[(AOFF) + mi][nj], 0, 0, 0);         \
} while (0)

    f32x4 acc[8][4];
    #pragma unroll
    for (int mi = 0; mi < 8; ++mi)
        #pragma unroll
        for (int nj = 0; nj < 4; ++nj)
            acc[mi][nj] = (f32x4){0.f, 0.f, 0.f, 0.f};

    STAGE_A(0, 0, 0); STAGE_A(0, 0, 1);
    STAGE_B(0, 0, 0); STAGE_B(0, 0, 1);
    STAGE_A(1, 1, 0); STAGE_A(1, 1, 1);
    asm volatile("s_waitcnt vmcnt(4)" ::: "memory");
    BARF();

    for (int t = 0; t < NT; ++t) {
        const int p = t & 1;
        const char* Ap = (const char*)&As[p][0];
        const char* Bp = (const char*)&Bs[p][0];
        bf16x8 am0k0[4], am1k0[4], bk0[4], am0k1[4], am1k1[4], bk1[4];

        // ph0: k0 frags; stage B(t+1)h0
        RD_A(am0k0, 0, fo0); RD_B(bk0, fo0); RD_A(am1k0, 4, fo0);
        if (t + 1 < NT) STAGE_B(t + 1, p ^ 1, 0);
        BARF();
        __builtin_amdgcn_s_setprio(1);
        MFMA16(am0k0, bk0, 0);
        __builtin_amdgcn_s_setprio(0);
        BARF();

        // ph1: k1 frags; stage B(t+1)h1; MFMA m1k0
        RD_A(am0k1, 0, fo1); RD_B(bk1, fo1); RD_A(am1k1, 4, fo1);
        if (t + 1 < NT) STAGE_B(t + 1, p ^ 1, 1);
        BARF();
        __builtin_amdgcn_s_setprio(1);
        MFMA16(am1k0, bk0, 4);
        __builtin_amdgcn_s_setprio(0);
        LGKM0();                       // all As[p]/Bs[p] reads complete
        BARF();

        // ph2: stage A(t+2)h0 into As[p]; MFMA m0k1
        if (t + 2 < NT) STAGE_A(t + 2, p, 0);
        __builtin_amdgcn_s_setprio(1);
        MFMA16(am0k1, bk1, 0);
        __builtin_amdgcn_s_setprio(0);
        BARF();

        // ph3: stage A(t+2)h1; MFMA m1k1; counted vmcnt; tile-end barrier
        if (t + 2 < NT) STAGE_A(t + 2, p, 1);
        __builtin_amdgcn_s_setprio(1);
        MFMA16(am1k1, bk1, 4);
        __builtin_amdgcn_s_setprio(0);
        if (t + 2 < NT) { asm volatile("s_waitcnt vmcnt(4)" ::: "memory"); }
        else            { asm volatile("s_waitcnt vmcnt(0)" ::: "memory"); }
        BARF();
    }

    #pragma unroll
    for (int mi = 0; mi < 8; ++mi) {
        const int r0 = m0 + wm * 128 + mi * 16 + fq * 4;
        #pragma unroll
        for (int nj = 0; nj < 4; ++nj) {
            const int col = n0 + wn * 64 + nj * 16 + fr;
            const float badd = (biasp != nullptr) ? biasp[col] : 0.f;
            __bf16* Co = isq ? q_bf : out_bf;
            #pragma unroll
            for (int r = 0; r < 4; ++r)
                Co[(size_t)(r0 + r) * Ncols + col] = (__bf16)(acc[mi][nj][r] + badd);
        }
    }
#undef STAGE_A
#undef STAGE_B
#undef RD_A
#undef RD_B
#undef MFMA16
}

// ---------------------------------------------------------------------------
// kv GEMM (CFG0, row-gather at 8192): kv = [tok; out] @ wkvt^T, 256 blocks.
// ---------------------------------------------------------------------------
__global__ __launch_bounds__(512, 2) void gemm_kv(
    const __bf16* __restrict__ tok, const __bf16* __restrict__ outm,
    const __bf16* __restrict__ wkvt, __bf16* __restrict__ kv_bf)
{
    __shared__ __align__(16) __bf16 As[2][256 * 64];
    __shared__ __align__(16) __bf16 Bs[2][256 * 64];
    constexpr int NT = 16, K = 1024, Ncols = 1024;
    const int tid = threadIdx.x;
    const int w = tid >> 6, lane = tid & 63;
    const int wm = w >> 2, wn = w & 3;
    const int fr = lane & 15, fq = lane >> 4;
    const int bid = blockIdx.x;
    const int c = bid & 7, s = bid >> 3;
    const int sq = s >> 2;                 // ntx = 4
    const int m0 = (c * 8 + sq) * 256;     // nty/8 = 8
    const int n0 = (s - sq * 4) * 256;
    const __bf16* Ab = (m0 >= 8192) ? (outm + (size_t)(m0 - 8192) * K)
                                    : (tok + (size_t)m0 * K);
    const __bf16* Btb = wkvt + (size_t)n0 * K;

    const int lrow = lane >> 3;
    const int lchunk = (lane & 7) ^ lrow;
    const int fo0 = ((fq ^ (lane & 7)) << 4);
    const int fo1 = (((4 + fq) ^ (lane & 7)) << 4);

#define STAGE_A(T2, PB, HALF) do {                                            \
    _Pragma("unroll")                                                         \
    for (int ld = (HALF) * 2; ld < (HALF) * 2 + 2; ++ld)                      \
        GLL(Ab + (size_t)(w * 32 + ld * 8 + lrow) * K + (T2) * 64 + lchunk * 8, \
            &As[PB][(w * 32 + ld * 8) * 64]);                                 \
} while (0)
#define STAGE_B(T2, PB, HALF) do {                                            \
    _Pragma("unroll")                                                         \
    for (int ld = (HALF) * 2; ld < (HALF) * 2 + 2; ++ld)                      \
        GLL(Btb + (size_t)(w * 32 + ld * 8 + lrow) * K + (T2) * 64 + lchunk * 8, \
            &Bs[PB][(w * 32 + ld * 8) * 64]);                                 \
} while (0)
#define RD_A(DST, MIOFF, FO) do {                                             \
    _Pragma("unroll")                                                         \
    for (int mi = 0; mi < 4; ++mi)                                            \
        (DST)[mi] = *(const bf16x8*)(Ap + ((wm * 128 + ((MIOFF) + mi) * 16 + fr) << 7) + (FO)); \
} while (0)
#define RD_B(DST, FO) do {                                                    \
    _Pragma("unroll")                                                         \
    for (int nj = 0; nj < 4; ++nj)                                            \
        (DST)[nj] = *(const bf16x8*)(Bp + ((wn * 64 + nj * 16 + fr) << 7) + (FO)); \
} while (0)
#define MFMA16(AFR, BFR, AOFF) do {                                           \
    _Pragma("unroll")                                                         \
    for (int mi = 0; mi < 4; ++mi)                                            \
        _Pragma("unroll")                                                     \
        for (int nj = 0; nj < 4; ++nj)                                        \
            acc[(AOFF) + mi][nj] = __builtin_amdgcn_mfma_f32_16x16x32_bf16(   \
                (AFR)[mi], (BFR)[nj], acc[(AOFF) + mi][nj], 0, 0, 0);         \
} while (0)

    f32x4 acc[8][4];
    #pragma unroll
    for (int mi = 0; mi < 8; ++mi)
        #pragma unroll
        for (int nj = 0; nj < 4; ++nj)
            acc[mi][nj] = (f32x4){0.f, 0.f, 0.f, 0.f};

    STAGE_A(0, 0, 0); STAGE_A(0, 0, 1);
    STAGE_B(0, 0, 0); STAGE_B(0, 0, 1);
    STAGE_A(1, 1, 0); STAGE_A(1, 1, 1);
    asm volatile("s_waitcnt vmcnt(4)" ::: "memory");
    BARF();

    for (int t = 0; t < NT; ++t) {
        const int p = t & 1;
        const char* Ap = (const char*)&As[p][0];
        const char* Bp = (const char*)&Bs[p][0];
        bf16x8 am0k0[4], am1k0[4], bk0[4], am0k1[4], am1k1[4], bk1[4];

        RD_A(am0k0, 0, fo0); RD_B(bk0, fo0); RD_A(am1k0, 4, fo0);
        if (t + 1 < NT) STAGE_B(t + 1, p ^ 1, 0);
        BARF();
        __builtin_amdgcn_s_setprio(1);
        MFMA16(am0k0, bk0, 0);
        __builtin_amdgcn_s_setprio(0);
        BARF();

        RD_A(am0k1, 0, fo1); RD_B(bk1, fo1); RD_A(am1k1, 4, fo1);
        if (t + 1 < NT) STAGE_B(t + 1, p ^ 1, 1);
        BARF();
        __builtin_amdgcn_s_setprio(1);
        MFMA16(am1k0, bk0, 4);
        __builtin_amdgcn_s_setprio(0);
        LGKM0();
        BARF();

        if (t + 2 < NT) STAGE_A(t + 2, p, 0);
        __builtin_amdgcn_s_setprio(1);
        MFMA16(am0k1, bk1, 0);
        __builtin_amdgcn_s_setprio(0);
        BARF();

        if (t + 2 < NT) STAGE_A(t + 2, p, 1);
        __builtin_amdgcn_s_setprio(1);
        MFMA16(am1k1, bk1, 4);
        __builtin_amdgcn_s_setprio(0);
        if (t + 2 < NT) { asm volatile("s_waitcnt vmcnt(4)" ::: "memory"); }
        else            { asm volatile("s_waitcnt vmcnt(0)" ::: "memory"); }
        BARF();
    }

    #pragma unroll
    for (int mi = 0; mi < 8; ++mi) {
        const int r0 = m0 + wm * 128 + mi * 16 + fq * 4;
        #pragma unroll
        for (int nj = 0; nj < 4; ++nj) {
            const int col = n0 + wn * 64 + nj * 16 + fr;
            #pragma unroll
            for (int r = 0; r < 4; ++r)
                kv_bf[(size_t)(r0 + r) * Ncols + col] = (__bf16)acc[mi][nj][r];
        }
    }
#undef STAGE_A
#undef STAGE_B
#undef RD_A
#undef RD_B
#undef MFMA16
}

// ---------------------------------------------------------------------------
// final GEMM, CFG1: BM=256 BN=128, 8 waves (4m x 2n), wave tile 64x64.
// M=8192, N=1024, K=512 -> 256 blocks (full machine).
// ---------------------------------------------------------------------------
__global__ __launch_bounds__(512, 2) void gemm_final(
    const __bf16* __restrict__ A,      // og [8192][512]
    const __bf16* __restrict__ Bt,     // woutt [1024][512]
    float* __restrict__ Cf)            // out [8192][1024] f32
{
    __shared__ __align__(16) __bf16 As[2][256 * 64];   // 64 KiB
    __shared__ __align__(16) __bf16 Bs[2][128 * 64];   // 32 KiB
    constexpr int NT = 8, K = 512, Ncols = 1024;
    const int tid = threadIdx.x;
    const int w = tid >> 6, lane = tid & 63;
    const int wm = w >> 1, wn = w & 1;
    const int fr = lane & 15, fq = lane >> 4;
    const int bid = blockIdx.x;
    const int c = bid & 7, s = bid >> 3;
    const int sq = s >> 3;                 // ntx = 8
    const int m0 = (c * 4 + sq) * 256;     // nty/8 = 4
    const int n0 = (s - sq * 8) * 128;
    const __bf16* Ab = A + (size_t)m0 * K;
    const __bf16* Btb = Bt + (size_t)n0 * K;

    const int lrow = lane >> 3;
    const int lchunk = (lane & 7) ^ lrow;
    const int fo0 = ((fq ^ (lane & 7)) << 4);
    const int fo1 = (((4 + fq) ^ (lane & 7)) << 4);

#define STAGE_A(T2, PB, HALF) do {                                            \
    _Pragma("unroll")                                                         \
    for (int ld = (HALF) * 2; ld < (HALF) * 2 + 2; ++ld)                      \
        GLL(Ab + (size_t)(w * 32 + ld * 8 + lrow) * K + (T2) * 64 + lchunk * 8, \
            &As[PB][(w * 32 + ld * 8) * 64]);                                 \
} while (0)
#define STAGE_B(T2, PB, HALF)                                                 \
    GLL(Btb + (size_t)(w * 16 + (HALF) * 8 + lrow) * K + (T2) * 64 + lchunk * 8, \
        &Bs[PB][(w * 16 + (HALF) * 8) * 64])
#define RD_A(DST, FO) do {                                                    \
    _Pragma("unroll")                                                         \
    for (int mi = 0; mi < 4; ++mi)                                            \
        (DST)[mi] = *(const bf16x8*)(Ap + ((wm * 64 + mi * 16 + fr) << 7) + (FO)); \
} while (0)
#define RD_B(DST, FO) do {                                                    \
    _Pragma("unroll")                                                         \
    for (int nj = 0; nj < 4; ++nj)                                            \
        (DST)[nj] = *(const bf16x8*)(Bp + ((wn * 64 + nj * 16 + fr) << 7) + (FO)); \
} while (0)
#define MFMA16C1(AFR, BFR) do {                                               \
    _Pragma("unroll")                                                         \
    for (int mi = 0; mi < 4; ++mi)                                            \
        _Pragma("unroll")                                                     \
        for (int nj = 0; nj < 4; ++nj)                                        \
            acc[mi][nj] = __builtin_amdgcn_mfma_f32_16x16x32_bf16(            \
                (AFR)[mi], (BFR)[nj], acc[mi][nj], 0, 0, 0);                  \
} while (0)

    f32x4 acc[4][4];
    #pragma unroll
    for (int mi = 0; mi < 4; ++mi)
        #pragma unroll
        for (int nj = 0; nj < 4; ++nj)
            acc[mi][nj] = (f32x4){0.f, 0.f, 0.f, 0.f};

    STAGE_A(0, 0, 0); STAGE_A(0, 0, 1);
    STAGE_B(0, 0, 0); STAGE_B(0, 0, 1);
    STAGE_A(1, 1, 0); STAGE_A(1, 1, 1);
    asm volatile("s_waitcnt vmcnt(4)" ::: "memory");
    BARF();

    for (int t = 0; t < NT; ++t) {
        const int p = t & 1;
        const char* Ap = (const char*)&As[p][0];
        const char* Bp = (const char*)&Bs[p][0];
        bf16x8 ak0[4], bk0[4], ak1[4], bk1[4];

        RD_A(ak0, fo0); RD_B(bk0, fo0);
        if (t + 1 < NT) STAGE_B(t + 1, p ^ 1, 0);
        BARF();
        __builtin_amdgcn_s_setprio(1);
        MFMA16C1(ak0, bk0);
        __builtin_amdgcn_s_setprio(0);
        BARF();

        RD_A(ak1, fo1); RD_B(bk1, fo1);
        if (t + 1 < NT) STAGE_B(t + 1, p ^ 1, 1);
        BARF();
        __builtin_amdgcn_s_setprio(1);
        MFMA16C1(ak1, bk1);
        __builtin_amdgcn_s_setprio(0);
        LGKM0();
        BARF();

        if (t + 2 < NT) { STAGE_A(t + 2, p, 0); STAGE_A(t + 2, p, 1); }
        if (t + 2 < NT) { asm volatile("s_waitcnt vmcnt(4)" ::: "memory"); }
        else            { asm volatile("s_waitcnt vmcnt(0)" ::: "memory"); }
        BARF();
    }

    #pragma unroll
    for (int mi = 0; mi < 4; ++mi) {
        const int r0 = m0 + wm * 64 + mi * 16 + fq * 4;
        #pragma unroll
        for (int nj = 0; nj < 4; ++nj) {
            const int col = n0 + wn * 64 + nj * 16 + fr;
            #pragma unroll
            for (int r = 0; r < 4; ++r)
                Cf[(size_t)(r0 + r) * Ncols + col] = acc[mi][nj][r];
        }
    }
#undef STAGE_A
#undef STAGE_B
#undef RD_A
#undef RD_B
#undef MFMA16C1
}

// ---------------------------------------------------------------------------
// Merged-heads attention: one 512-thread block per (b,n) site; wave = head.
// ---------------------------------------------------------------------------
__global__ __launch_bounds__(512) void attn_kernel(
    const __bf16* __restrict__ q,     // [8192, 512]
    const __bf16* __restrict__ kv,    // [16384, 1024]  (k | v)
    const float* __restrict__ gates,  // [8192, 8]
    const float* __restrict__ knw,    // [64]
    __bf16* __restrict__ og)          // [8192, 512]
{
    const int bn = blockIdx.x;        // 0..1023
    const int tid = threadIdx.x;
    const int h = tid >> 6, lane = tid & 63;

    __shared__ __align__(16) __bf16 qs[8][520];
    __shared__ __align__(16) __bf16 kvs[16][1032];
    __shared__ float ssm[8][8][17];   // [h][l][m]
    __shared__ float kn[64];
    __shared__ float gs[64];          // [l*8+h]

    {
        const int l = tid >> 6, c8 = tid & 63;
        *(bf16x8*)&qs[l][c8 * 8] =
            *(const bf16x8*)(q + ((size_t)(l * BN_TOK + bn)) * INNER_ + c8 * 8);
    }
    #pragma unroll
    for (int i = 0; i < 4; ++i) {
        const int g = tid + i * 512;
        const int m = g >> 7, c8 = g & 127;
        *(bf16x8*)&kvs[m][c8 * 8] =
            *(const bf16x8*)(kv + ((size_t)(m * BN_TOK + bn)) * 1024 + c8 * 8);
    }
    if (tid < 64) {
        kn[tid] = knw[tid];
        gs[tid] = gates[((size_t)((tid >> 3) * BN_TOK + bn)) * H_ + (tid & 7)];
    }
    __syncthreads();

    const int m = lane & 15, grp = lane >> 4;

    float s2 = 0.f;
    #pragma unroll
    for (int j = 0; j < 16; ++j) {
        float v = (float)kvs[m][h * DH_ + grp * 16 + j];
        s2 = fmaf(v, v, s2);
    }
    s2 += __shfl_xor(s2, 16);
    s2 += __shfl_xor(s2, 32);
    const float kscale = rsqrtf(s2 * (1.f / DH_) + EPS) * SCALE_;

    const int l0 = grp, l1 = grp + 4;
    float sim0 = 0.f, sim1 = 0.f;
    #pragma unroll
    for (int d = 0; d < DH_; ++d) {
        const float kf = (float)kvs[m][h * DH_ + d] * kn[d];
        sim0 = fmaf((float)qs[l0][h * DH_ + d], kf, sim0);
        sim1 = fmaf((float)qs[l1][h * DH_ + d], kf, sim1);
    }
    sim0 *= kscale; sim1 *= kscale;

    float mx0 = sim0, mx1 = sim1;
    #pragma unroll
    for (int o = 1; o < 16; o <<= 1) {
        mx0 = fmaxf(mx0, __shfl_xor(mx0, o));
        mx1 = fmaxf(mx1, __shfl_xor(mx1, o));
    }
    float e0 = expf(sim0 - mx0), e1 = expf(sim1 - mx1);
    float sm0 = e0, sm1 = e1;
    #pragma unroll
    for (int o = 1; o < 16; o <<= 1) {
        sm0 += __shfl_xor(sm0, o);
        sm1 += __shfl_xor(sm1, o);
    }
    ssm[h][l0][m] = e0 / sm0;
    ssm[h][l1][m] = e1 / sm1;

    float vf[16];
    #pragma unroll
    for (int mm = 0; mm < 16; ++mm)
        vf[mm] = (float)kvs[mm][INNER_ + h * DH_ + lane];
    #pragma unroll
    for (int l = 0; l < 8; ++l) {
        float o = 0.f;
        #pragma unroll
        for (int mm = 0; mm < 16; ++mm) o = fmaf(ssm[h][l][mm], vf[mm], o);
        og[((size_t)(l * BN_TOK + bn)) * INNER_ + h * DH_ + lane] =
            (__bf16)(o * gs[l * 8 + h]);
    }
}

// ---------------------------------------------------------------------------
extern "C" void kernel_launch(void* const* d_in, const int* in_sizes, int n_in,
                              void* d_out, int out_size, void* d_ws, size_t ws_size,
                              hipStream_t stream)
{
    const float* tokens = (const float*)d_in[0];  // [8,2,512,1024]
    const float* w_net  = (const float*)d_in[1];  // [8,1024,1024]
    const float* b_net  = (const float*)d_in[2];  // [8,1024]
    const float* norm_w = (const float*)d_in[3];  // [1024]
    const float* wq     = (const float*)d_in[4];  // [1024,512]
    const float* wkv    = (const float*)d_in[5];  // [1024,1024]
    const float* knw    = (const float*)d_in[6];  // [64]
    const float* wg     = (const float*)d_in[7];  // [1024,8]
    const float* wout   = (const float*)d_in[8];  // [512,1024]
    float* out = (float*)d_out;                   // [8,2,512,1024]

    char* ws = (char*)d_ws;
    __bf16* tok_bf  = (__bf16*)(ws);                         // 16,777,216 B
    __bf16* tn_bf   = (__bf16*)(ws + 16777216);              // 16,777,216
    __bf16* out_bf  = (__bf16*)(ws + 33554432);              // 16,777,216
    __bf16* q_bf    = (__bf16*)(ws + 50331648);              //  8,388,608
    __bf16* kv_bf   = (__bf16*)(ws + 58720256);              // 33,554,432
    __bf16* og_bf   = (__bf16*)(ws + 92274688);              //  8,388,608
    __bf16* wnet_bf = (__bf16*)(ws + 100663296);             // 16,777,216
    __bf16* wqt_bf  = (__bf16*)(ws + 117440512);             //  1,048,576
    __bf16* wkvt_bf = (__bf16*)(ws + 118489088);             //  2,097,152
    __bf16* woutt_bf= (__bf16*)(ws + 120586240);             //  1,048,576
    float*  ws_g    = (float*)(ws + 121667584);              //    262,144
    __bf16* wgT_bf  = (__bf16*)(ws + 121929728);             //     32,768

    // 1. consolidated prep (rs + weight conversions + wgT)
    prep_kernel<<<12352, 256, 0, stream>>>(tokens, norm_w, w_net, wq, wkv, wout, wg,
                                           tok_bf, tn_bf, wnet_bf, wqt_bf,
                                           wkvt_bf, woutt_bf, wgT_bf);
    // 2. member + q + gates (256 blocks, full machine)
    gemm_fused<<<256, 512, 0, stream>>>(tok_bf, tn_bf, wnet_bf, wqt_bf, b_net,
                                        wgT_bf, out_bf, q_bf, ws_g);
    // 3. kv = [tok; out] @ wkv (256 blocks)
    gemm_kv<<<256, 512, 0, stream>>>(tok_bf, out_bf, wkvt_bf, kv_bf);
    // 4. attention + gating
    attn_kernel<<<BN_TOK, 512, 0, stream>>>(q_bf, kv_bf, ws_g, knw, og_bf);
    // 5. pooled = og @ wout -> d_out (f32, 256 blocks CFG1)
    gemm_final<<<256, 512, 0, stream>>>(og_bf, woutt_bf, out);
}